// Round 1
// baseline (784.730 us; speedup 1.0000x reference)
//
#include <hip/hip_runtime.h>

typedef unsigned short u16;
typedef __attribute__((ext_vector_type(4))) unsigned short us4;
typedef __attribute__((ext_vector_type(8))) unsigned short us8;
typedef __attribute__((ext_vector_type(8))) __bf16 bf16x8;
typedef __attribute__((ext_vector_type(4))) float f32x4;

#define L2E 1.4426950408889634f

__device__ __forceinline__ u16 f2b(float f) {
  unsigned u = __builtin_bit_cast(unsigned, f);
  u += 0x7fffu + ((u >> 16) & 1u);          // round-to-nearest-even
  return (u16)(u >> 16);
}
__device__ __forceinline__ float b2f(u16 s) {
  unsigned u = ((unsigned)s) << 16;
  return __builtin_bit_cast(float, u);
}

// ---------------------------------------------------------------------------
// TN GEMM: C[M][N] = A[M][K] @ B[N][K]^T, f32 inputs converted to bf16 in LDS.
// MODE 0: epilogue = RoPE + scatter to per-head q/k/v bf16 arrays (QKV GEMM)
// MODE 1: plain f32 store to Cout                                  (OUT GEMM)
// Tile 128x128xBK32, 256 threads (4 waves, 2x2 of 64x64), mfma 16x16x32 bf16.
// LDS stride 40 (bf16): 80B rows -> 8-row bank period, conflict-free b128.
// ---------------------------------------------------------------------------
template<int MODE>
__global__ __launch_bounds__(256, 2)
void gemm_tn(const float* __restrict__ A, const float* __restrict__ Bm,
             float* __restrict__ Cout,
             u16* __restrict__ qb, u16* __restrict__ kb, u16* __restrict__ vb,
             const float* __restrict__ cosT, const float* __restrict__ sinT,
             int M, int N, int K)
{
  __shared__ u16 As[128 * 40];
  __shared__ u16 Bs[128 * 40];
  const int tid  = threadIdx.x;
  const int lane = tid & 63;
  const int wid  = tid >> 6;
  const int m0 = blockIdx.y * 128;
  const int n0 = blockIdx.x * 128;
  const int wm = (wid >> 1) * 64;
  const int wn = (wid & 1) * 64;

  f32x4 acc[4][4];
#pragma unroll
  for (int i = 0; i < 4; ++i)
#pragma unroll
    for (int j = 0; j < 4; ++j) acc[i][j] = (f32x4)0.f;

  const int srow = tid >> 3;        // 0..31
  const int sc4  = (tid & 7) * 4;   // 0..28
  const float* Ap = A  + (long)(m0 + srow) * K + sc4;
  const float* Bp = Bm + (long)(n0 + srow) * K + sc4;

  for (int k0 = 0; k0 < K; k0 += 32) {
#pragma unroll
    for (int p = 0; p < 4; ++p) {
      float4 av = *(const float4*)(Ap + (long)(p * 32) * K + k0);
      float4 bv = *(const float4*)(Bp + (long)(p * 32) * K + k0);
      us4 a4 = { f2b(av.x), f2b(av.y), f2b(av.z), f2b(av.w) };
      us4 b4 = { f2b(bv.x), f2b(bv.y), f2b(bv.z), f2b(bv.w) };
      *(us4*)(As + (srow + p * 32) * 40 + sc4) = a4;
      *(us4*)(Bs + (srow + p * 32) * 40 + sc4) = b4;
    }
    __syncthreads();
    bf16x8 af[4], bfr[4];
#pragma unroll
    for (int mi = 0; mi < 4; ++mi)
      af[mi] = *(const bf16x8*)(As + (wm + mi * 16 + (lane & 15)) * 40 + 8 * (lane >> 4));
#pragma unroll
    for (int ni = 0; ni < 4; ++ni)
      bfr[ni] = *(const bf16x8*)(Bs + (wn + ni * 16 + (lane & 15)) * 40 + 8 * (lane >> 4));
#pragma unroll
    for (int mi = 0; mi < 4; ++mi)
#pragma unroll
      for (int ni = 0; ni < 4; ++ni)
        acc[mi][ni] = __builtin_amdgcn_mfma_f32_16x16x32_bf16(af[mi], bfr[ni], acc[mi][ni], 0, 0, 0);
    __syncthreads();
  }

  if (MODE == 0) {
    // whole 128-col tile is one (w, head) slice: n = w*2048 + h*128 + d
    const int w  = n0 >> 11;
    const int hh = (n0 >> 7) & 15;
#pragma unroll
    for (int mi = 0; mi < 4; ++mi) {
      const int rowb = m0 + wm + mi * 16 + (lane >> 4) * 4;
#pragma unroll
      for (int ni = 0; ni < 4; ++ni) {
        const int d = wn + ni * 16 + (lane & 15);
#pragma unroll
        for (int r = 0; r < 4; ++r) {
          float val = acc[mi][ni][r];
          float oth = __shfl_xor(val, 1);   // RoPE partner (d^1), uniform control
          const int tok = rowb + r;
          const int s   = tok & 2047;
          const long idx = ((long)(((tok >> 11) << 4) | hh) * 2048 + s) * 128 + d;
          if (w == 2) {
            vb[idx] = f2b(val);
          } else {
            float c  = cosT[s * 64 + (d >> 1)];
            float sn = sinT[s * 64 + (d >> 1)];
            float res = (d & 1) ? (oth * sn + val * c) : (val * c - oth * sn);
            ((w == 0) ? qb : kb)[idx] = f2b(res);
          }
        }
      }
    }
  } else {
#pragma unroll
    for (int mi = 0; mi < 4; ++mi) {
      const int rowb = m0 + wm + mi * 16 + (lane >> 4) * 4;
#pragma unroll
      for (int ni = 0; ni < 4; ++ni) {
        const int col = n0 + wn + ni * 16 + (lane & 15);
#pragma unroll
        for (int r = 0; r < 4; ++r)
          Cout[(long)(rowb + r) * N + col] = acc[mi][ni][r];
      }
    }
  }
}

// ---------------------------------------------------------------------------
// Causal flash attention fwd. One block = (bh, q-tile of 64 rows), 4 waves,
// each wave owns 16 q-rows. KV tiles of 32. mfma 16x16x32 bf16, f32 softmax.
// ---------------------------------------------------------------------------
__global__ __launch_bounds__(256, 2)
void flash_attn(const u16* __restrict__ qb, const u16* __restrict__ kb,
                const u16* __restrict__ vb, float* __restrict__ a_ws)
{
  __shared__ u16 Ks[32 * 136];   // [kv][d], stride 136 for bank spread
  __shared__ u16 Vs[128 * 40];   // transposed [d][kv], stride 40
  __shared__ u16 Ps[64 * 40];    // [qrow][kv]
  const int tid  = threadIdx.x;
  const int lane = tid & 63;
  const int wv   = tid >> 6;
  const int qt = blockIdx.x;
  const int bh = blockIdx.y;
  const int q0 = qt * 64;
  const long basek = (long)bh * 2048 * 128;

  bf16x8 qf[4];
  {
    const u16* qptr = qb + basek + (long)(q0 + wv * 16 + (lane & 15)) * 128 + 8 * (lane >> 4);
#pragma unroll
    for (int ks = 0; ks < 4; ++ks) qf[ks] = *(const bf16x8*)(qptr + 32 * ks);
  }
  f32x4 acco[8];
#pragma unroll
  for (int i = 0; i < 8; ++i) acco[i] = (f32x4)0.f;
  float mrow[4] = {-1e30f, -1e30f, -1e30f, -1e30f};
  float ssum[4] = {0.f, 0.f, 0.f, 0.f};

  const int srow = tid >> 3;        // 0..31 kv row
  const int sc   = (tid & 7) * 16;  // d block
  const int nt = 2 * qt + 2;

  for (int t = 0; t < nt; ++t) {
    const int kv0 = t * 32;
    {
      const u16* kp = kb + basek + (long)(kv0 + srow) * 128 + sc;
      const u16* vp = vb + basek + (long)(kv0 + srow) * 128 + sc;
      us8 k0v = *(const us8*)kp;
      us8 k1v = *(const us8*)(kp + 8);
      *(us8*)(Ks + srow * 136 + sc)     = k0v;
      *(us8*)(Ks + srow * 136 + sc + 8) = k1v;
      us8 v0v = *(const us8*)vp;
      us8 v1v = *(const us8*)(vp + 8);
#pragma unroll
      for (int j = 0; j < 8; ++j) Vs[(sc + j) * 40 + srow] = v0v[j];
#pragma unroll
      for (int j = 0; j < 8; ++j) Vs[(sc + 8 + j) * 40 + srow] = v1v[j];
    }
    __syncthreads();

    f32x4 accs[2];
    accs[0] = (f32x4)0.f; accs[1] = (f32x4)0.f;
#pragma unroll
    for (int ni = 0; ni < 2; ++ni)
#pragma unroll
      for (int ks = 0; ks < 4; ++ks) {
        bf16x8 kf = *(const bf16x8*)(Ks + (ni * 16 + (lane & 15)) * 136 + 8 * (lane >> 4) + 32 * ks);
        accs[ni] = __builtin_amdgcn_mfma_f32_16x16x32_bf16(qf[ks], kf, accs[ni], 0, 0, 0);
      }

    const int qrb = q0 + wv * 16 + (lane >> 4) * 4;
    float sv[2][4];
    float rmax[4] = {-1e30f, -1e30f, -1e30f, -1e30f};
#pragma unroll
    for (int ni = 0; ni < 2; ++ni) {
      const int kvc = kv0 + ni * 16 + (lane & 15);
#pragma unroll
      for (int r = 0; r < 4; ++r) {
        float s = accs[ni][r] * 0.08838834764831845f;   // 1/sqrt(128)
        if (kvc > qrb + r) s = -1e30f;                  // causal mask
        sv[ni][r] = s;
        rmax[r] = fmaxf(rmax[r], s);
      }
    }
#pragma unroll
    for (int r = 0; r < 4; ++r) {
      rmax[r] = fmaxf(rmax[r], __shfl_xor(rmax[r], 1));
      rmax[r] = fmaxf(rmax[r], __shfl_xor(rmax[r], 2));
      rmax[r] = fmaxf(rmax[r], __shfl_xor(rmax[r], 4));
      rmax[r] = fmaxf(rmax[r], __shfl_xor(rmax[r], 8));
    }
    float alpha[4], psum[4];
#pragma unroll
    for (int r = 0; r < 4; ++r) {
      float mn = fmaxf(mrow[r], rmax[r]);
      alpha[r] = exp2f((mrow[r] - mn) * L2E);
      mrow[r] = mn;
      psum[r] = 0.f;
    }
#pragma unroll
    for (int ni = 0; ni < 2; ++ni) {
#pragma unroll
      for (int r = 0; r < 4; ++r) {
        float p = exp2f((sv[ni][r] - mrow[r]) * L2E);
        psum[r] += p;
        Ps[(wv * 16 + (lane >> 4) * 4 + r) * 40 + ni * 16 + (lane & 15)] = f2b(p);
      }
    }
#pragma unroll
    for (int r = 0; r < 4; ++r) {
      psum[r] += __shfl_xor(psum[r], 1);
      psum[r] += __shfl_xor(psum[r], 2);
      psum[r] += __shfl_xor(psum[r], 4);
      psum[r] += __shfl_xor(psum[r], 8);
      ssum[r] = ssum[r] * alpha[r] + psum[r];
    }
#pragma unroll
    for (int i = 0; i < 8; ++i)
#pragma unroll
      for (int r = 0; r < 4; ++r) acco[i][r] *= alpha[r];

    // P written/read by the same wave's 16 rows: intra-wave LDS ordering is
    // in-order per wave; compiler keeps order (same array, possible alias).
    bf16x8 pf = *(const bf16x8*)(Ps + (wv * 16 + (lane & 15)) * 40 + 8 * (lane >> 4));
#pragma unroll
    for (int ni = 0; ni < 8; ++ni) {
      bf16x8 vf = *(const bf16x8*)(Vs + (ni * 16 + (lane & 15)) * 40 + 8 * (lane >> 4));
      acco[ni] = __builtin_amdgcn_mfma_f32_16x16x32_bf16(pf, vf, acco[ni], 0, 0, 0);
    }
    __syncthreads();
  }

  const int b = bh >> 4, hh = bh & 15;
#pragma unroll
  for (int r = 0; r < 4; ++r) {
    const float inv = 1.f / ssum[r];
    const long tok = (long)((b << 11) | (q0 + wv * 16 + (lane >> 4) * 4 + r));
#pragma unroll
    for (int ni = 0; ni < 8; ++ni) {
      const int col = hh * 128 + ni * 16 + (lane & 15);
      a_ws[tok * 2048 + col] = acco[ni][r] * inv;
    }
  }
}

// ---------------------------------------------------------------------------
// Holographic path, exact time-domain form of irfft(conj(qf)*kf*vf):
//   c[s]    = sum_j k[j] * v[(s-j) & 127]          (circular convolution)
//   holo[t] = (1/128) * sum_tau q[tau] * c[(t+tau) & 127]
// One wave per (b,h,s) row; q,k,v,c staged in LDS (f32).
// ---------------------------------------------------------------------------
__global__ __launch_bounds__(256, 2)
void holo_kernel(const u16* __restrict__ qb, const u16* __restrict__ kb,
                 const u16* __restrict__ vb, float* __restrict__ h_ws)
{
  __shared__ float qs[4][128], ksd[4][128], vs[4][128], cs[4][128];
  const int tid = threadIdx.x, lane = tid & 63, wv = tid >> 6;
  const long row  = (long)blockIdx.x * 4 + wv;   // bh*2048 + s
  const long base = row * 128;
  qs [wv][lane]      = b2f(qb[base + lane]);
  qs [wv][lane + 64] = b2f(qb[base + lane + 64]);
  ksd[wv][lane]      = b2f(kb[base + lane]);
  ksd[wv][lane + 64] = b2f(kb[base + lane + 64]);
  vs [wv][lane]      = b2f(vb[base + lane]);
  vs [wv][lane + 64] = b2f(vb[base + lane + 64]);
  __syncthreads();
  const int s1 = lane, s2 = lane + 64;
  float c1 = 0.f, c2 = 0.f;
#pragma unroll 4
  for (int j = 0; j < 128; ++j) {
    float kj = ksd[wv][j];
    c1 = fmaf(kj, vs[wv][(s1 - j) & 127], c1);
    c2 = fmaf(kj, vs[wv][(s2 - j) & 127], c2);
  }
  cs[wv][s1] = c1;
  cs[wv][s2] = c2;
  __syncthreads();
  float h1 = 0.f, h2 = 0.f;
#pragma unroll 4
  for (int j = 0; j < 128; ++j) {
    float qj = qs[wv][j];
    h1 = fmaf(qj, cs[wv][(s1 + j) & 127], h1);
    h2 = fmaf(qj, cs[wv][(s2 + j) & 127], h2);
  }
  const int bh = (int)(row >> 11);
  const int s  = (int)(row & 2047);
  const long irow = (long)(((bh >> 4) << 11) | s);
  const int colb  = (bh & 15) * 128;
  h_ws[irow * 2048 + colb + s1] = h1 * 0.0078125f;   // 1/128
  h_ws[irow * 2048 + colb + s2] = h2 * 0.0078125f;
}

// ---------------------------------------------------------------------------
// Fused LayerNorm(a), LayerNorm(h), sigmoid-clip blend; writes into a in-place
// One block per token row (2048 f32), 256 threads x 8 elements.
// ---------------------------------------------------------------------------
__global__ __launch_bounds__(256)
void ln_blend(float* __restrict__ a, const float* __restrict__ h,
              const float* __restrict__ gate,
              const float* __restrict__ ga, const float* __restrict__ ba,
              const float* __restrict__ gh, const float* __restrict__ bhv)
{
  const int tid = threadIdx.x;
  const long roff = (long)blockIdx.x * 2048 + tid * 8;
  float av[8], hv[8];
  {
    float4 t0 = *(const float4*)(a + roff);
    float4 t1 = *(const float4*)(a + roff + 4);
    av[0]=t0.x; av[1]=t0.y; av[2]=t0.z; av[3]=t0.w;
    av[4]=t1.x; av[5]=t1.y; av[6]=t1.z; av[7]=t1.w;
    float4 t2 = *(const float4*)(h + roff);
    float4 t3 = *(const float4*)(h + roff + 4);
    hv[0]=t2.x; hv[1]=t2.y; hv[2]=t2.z; hv[3]=t2.w;
    hv[4]=t3.x; hv[5]=t3.y; hv[6]=t3.z; hv[7]=t3.w;
  }
  float sa = 0.f, sa2 = 0.f, sh = 0.f, sh2 = 0.f;
#pragma unroll
  for (int i = 0; i < 8; ++i) {
    sa += av[i]; sa2 += av[i] * av[i];
    sh += hv[i]; sh2 += hv[i] * hv[i];
  }
#pragma unroll
  for (int o = 1; o < 64; o <<= 1) {
    sa += __shfl_xor(sa, o); sa2 += __shfl_xor(sa2, o);
    sh += __shfl_xor(sh, o); sh2 += __shfl_xor(sh2, o);
  }
  __shared__ float red[4][4];
  const int wv = tid >> 6;
  if ((tid & 63) == 0) { red[0][wv] = sa; red[1][wv] = sa2; red[2][wv] = sh; red[3][wv] = sh2; }
  __syncthreads();
  sa  = red[0][0] + red[0][1] + red[0][2] + red[0][3];
  sa2 = red[1][0] + red[1][1] + red[1][2] + red[1][3];
  sh  = red[2][0] + red[2][1] + red[2][2] + red[2][3];
  sh2 = red[3][0] + red[3][1] + red[3][2] + red[3][3];
  const float inv = 1.f / 2048.f;
  float ma = sa * inv,  va = sa2 * inv - ma * ma;
  float mh = sh * inv,  vh = sh2 * inv - mh * mh;
  float ra = rsqrtf(va + 1e-5f), rh = rsqrtf(vh + 1e-5f);
  float g = 1.f / (1.f + __expf(-gate[0]));
  g = fminf(fmaxf(g, 0.05f), 0.95f);
  const int j0 = tid * 8;
  float ov[8];
#pragma unroll
  for (int i = 0; i < 8; ++i) {
    float aa = (av[i] - ma) * ra * ga[j0 + i] + ba[j0 + i];
    float hn = (hv[i] - mh) * rh * gh[j0 + i] + bhv[j0 + i];
    ov[i] = (1.f - g) * aa + g * hn;
  }
  float4 o0 = { ov[0], ov[1], ov[2], ov[3] };
  float4 o1 = { ov[4], ov[5], ov[6], ov[7] };
  *(float4*)(a + roff)     = o0;
  *(float4*)(a + roff + 4) = o1;
}

// ---------------------------------------------------------------------------
extern "C" void kernel_launch(void* const* d_in, const int* in_sizes, int n_in,
                              void* d_out, int out_size, void* d_ws, size_t ws_size,
                              hipStream_t stream)
{
  const float* x    = (const float*)d_in[0];
  const float* cosT = (const float*)d_in[1];
  const float* sinT = (const float*)d_in[2];
  const float* qkvw = (const float*)d_in[3];
  const float* outw = (const float*)d_in[4];
  const float* gate = (const float*)d_in[5];
  const float* ga   = (const float*)d_in[6];
  const float* ba   = (const float*)d_in[7];
  const float* gh   = (const float*)d_in[8];
  const float* bhv  = (const float*)d_in[9];
  float* out = (float*)d_out;

  // workspace layout (112 MiB total):
  //   [0,16M)   q bf16 [32][2048][128]
  //   [16,32M)  k bf16
  //   [32,48M)  v bf16
  //   [48,80M)  a f32 [4096][2048]  (attention out -> blend in-place)
  //   [80,112M) h f32 [4096][2048]  (holo out)
  char* w = (char*)d_ws;
  u16* qb = (u16*)w;
  u16* kb = qb + (1u << 23);
  u16* vb = kb + (1u << 23);
  float* a_ws = (float*)(w + 50331648);
  float* h_ws = a_ws + (1u << 23);

  gemm_tn<0><<<dim3(48, 32), 256, 0, stream>>>(x, qkvw, nullptr, qb, kb, vb,
                                               cosT, sinT, 4096, 6144, 2048);
  flash_attn<<<dim3(32, 32), 256, 0, stream>>>(qb, kb, vb, a_ws);
  holo_kernel<<<16384, 256, 0, stream>>>(qb, kb, vb, h_ws);
  ln_blend<<<4096, 256, 0, stream>>>(a_ws, h_ws, gate, ga, ba, gh, bhv);
  gemm_tn<1><<<dim3(16, 32), 256, 0, stream>>>(a_ws, outw, out,
                                               nullptr, nullptr, nullptr,
                                               nullptr, nullptr, 4096, 2048, 2048);
}

// Round 2
// 572.232 us; speedup vs baseline: 1.3713x; 1.3713x over previous
//
#include <hip/hip_runtime.h>

typedef unsigned short u16;
typedef __attribute__((ext_vector_type(4))) unsigned short us4;
typedef __attribute__((ext_vector_type(8))) unsigned short us8;
typedef __attribute__((ext_vector_type(8))) __bf16 bf16x8;
typedef __attribute__((ext_vector_type(4))) float f32x4;

#define L2E 1.4426950408889634f

__device__ __forceinline__ u16 f2b(float f) {
  unsigned u = __builtin_bit_cast(unsigned, f);
  u += 0x7fffu + ((u >> 16) & 1u);          // round-to-nearest-even
  return (u16)(u >> 16);
}
__device__ __forceinline__ float b2f(u16 s) {
  unsigned u = ((unsigned)s) << 16;
  return __builtin_bit_cast(float, u);
}

// ---------------------------------------------------------------------------
// TN GEMM: C[M][N] = A[M][K] @ B[N][K]^T, f32 inputs converted to bf16 in LDS.
// MODE 0: epilogue = RoPE + scatter to per-head q/k/v bf16 arrays (QKV GEMM)
// MODE 1: plain f32 store to Cout                                  (OUT GEMM)
// ---------------------------------------------------------------------------
template<int MODE>
__global__ __launch_bounds__(256, 2)
void gemm_tn(const float* __restrict__ A, const float* __restrict__ Bm,
             float* __restrict__ Cout,
             u16* __restrict__ qb, u16* __restrict__ kb, u16* __restrict__ vb,
             const float* __restrict__ cosT, const float* __restrict__ sinT,
             int M, int N, int K)
{
  __shared__ u16 As[128 * 40];
  __shared__ u16 Bs[128 * 40];
  const int tid  = threadIdx.x;
  const int lane = tid & 63;
  const int wid  = tid >> 6;
  const int m0 = blockIdx.y * 128;
  const int n0 = blockIdx.x * 128;
  const int wm = (wid >> 1) * 64;
  const int wn = (wid & 1) * 64;

  f32x4 acc[4][4];
#pragma unroll
  for (int i = 0; i < 4; ++i)
#pragma unroll
    for (int j = 0; j < 4; ++j) acc[i][j] = (f32x4)0.f;

  const int srow = tid >> 3;        // 0..31
  const int sc4  = (tid & 7) * 4;   // 0..28
  const float* Ap = A  + (long)(m0 + srow) * K + sc4;
  const float* Bp = Bm + (long)(n0 + srow) * K + sc4;

  for (int k0 = 0; k0 < K; k0 += 32) {
#pragma unroll
    for (int p = 0; p < 4; ++p) {
      float4 av = *(const float4*)(Ap + (long)(p * 32) * K + k0);
      float4 bv = *(const float4*)(Bp + (long)(p * 32) * K + k0);
      us4 a4 = { f2b(av.x), f2b(av.y), f2b(av.z), f2b(av.w) };
      us4 b4 = { f2b(bv.x), f2b(bv.y), f2b(bv.z), f2b(bv.w) };
      *(us4*)(As + (srow + p * 32) * 40 + sc4) = a4;
      *(us4*)(Bs + (srow + p * 32) * 40 + sc4) = b4;
    }
    __syncthreads();
    bf16x8 af[4], bfr[4];
#pragma unroll
    for (int mi = 0; mi < 4; ++mi)
      af[mi] = *(const bf16x8*)(As + (wm + mi * 16 + (lane & 15)) * 40 + 8 * (lane >> 4));
#pragma unroll
    for (int ni = 0; ni < 4; ++ni)
      bfr[ni] = *(const bf16x8*)(Bs + (wn + ni * 16 + (lane & 15)) * 40 + 8 * (lane >> 4));
#pragma unroll
    for (int mi = 0; mi < 4; ++mi)
#pragma unroll
      for (int ni = 0; ni < 4; ++ni)
        acc[mi][ni] = __builtin_amdgcn_mfma_f32_16x16x32_bf16(af[mi], bfr[ni], acc[mi][ni], 0, 0, 0);
    __syncthreads();
  }

  if (MODE == 0) {
    const int w  = n0 >> 11;
    const int hh = (n0 >> 7) & 15;
#pragma unroll
    for (int mi = 0; mi < 4; ++mi) {
      const int rowb = m0 + wm + mi * 16 + (lane >> 4) * 4;
#pragma unroll
      for (int ni = 0; ni < 4; ++ni) {
        const int d = wn + ni * 16 + (lane & 15);
#pragma unroll
        for (int r = 0; r < 4; ++r) {
          float val = acc[mi][ni][r];
          float oth = __shfl_xor(val, 1);   // RoPE partner (d^1), uniform control
          const int tok = rowb + r;
          const int s   = tok & 2047;
          const long idx = ((long)(((tok >> 11) << 4) | hh) * 2048 + s) * 128 + d;
          if (w == 2) {
            vb[idx] = f2b(val);
          } else {
            float c  = cosT[s * 64 + (d >> 1)];
            float sn = sinT[s * 64 + (d >> 1)];
            float res = (d & 1) ? (oth * sn + val * c) : (val * c - oth * sn);
            ((w == 0) ? qb : kb)[idx] = f2b(res);
          }
        }
      }
    }
  } else {
#pragma unroll
    for (int mi = 0; mi < 4; ++mi) {
      const int rowb = m0 + wm + mi * 16 + (lane >> 4) * 4;
#pragma unroll
      for (int ni = 0; ni < 4; ++ni) {
        const int col = n0 + wn + ni * 16 + (lane & 15);
#pragma unroll
        for (int r = 0; r < 4; ++r)
          Cout[(long)(rowb + r) * N + col] = acc[mi][ni][r];
      }
    }
  }
}

// ---------------------------------------------------------------------------
// Causal flash attention v2 — swapped-operand S^T = mfma(K, Q).
// Block = (bh, q-tile of 64 rows), 4 waves x 16 q-rows. KV tiles of 64.
// Lane layout after S^T mfma: lane holds S^T[kv=4g+r][q=c] (c=lane&15,
// g=lane>>4) -> per-q softmax is a local 16-reduce + shfl_xor(16,32).
// P written as one ds_write_b64 per lane per 16-kv block (cols 4g..4g+3),
// read back as contiguous b128 A-fragments for PV. V staged transposed via
// packed u32 kv-pairs (conflict-free). 2 barriers per 64-kv tile.
// ---------------------------------------------------------------------------
__global__ __launch_bounds__(256, 3)
void flash_attn(const u16* __restrict__ qb, const u16* __restrict__ kb,
                const u16* __restrict__ vb, float* __restrict__ a_ws)
{
  __shared__ u16 Ks[64 * 140];   // [kv][d]   stride 140
  __shared__ u16 Vs[128 * 72];   // [d][kv]   stride 72 (transposed)
  __shared__ u16 Ps[64 * 72];    // [qrow][kv] stride 72
  const int tid  = threadIdx.x;
  const int lane = tid & 63;
  const int wv   = tid >> 6;
  const int c    = lane & 15;
  const int g    = lane >> 4;
  const int bh = blockIdx.x;
  const int qt = 31 - blockIdx.y;          // biggest blocks dispatch first
  const int q0 = qt * 64;
  const long basek = (long)bh * 2048 * 128;

  // Q fragment (A-style layout; serves as B operand of mfma(K,Q))
  bf16x8 qf[4];
  {
    const u16* qptr = qb + basek + (long)(q0 + wv * 16 + c) * 128 + 8 * g;
#pragma unroll
    for (int ks = 0; ks < 4; ++ks) qf[ks] = *(const bf16x8*)(qptr + 32 * ks);
  }
  f32x4 acco[8];
#pragma unroll
  for (int i = 0; i < 8; ++i) acco[i] = (f32x4)0.f;
  float m = -1e30f, l = 0.f;       // per lane: stats of q-row (wv*16 + c)

  const int skv = tid >> 2;          // K staging: kv row 0..63
  const int sdu = (tid & 3) * 32;    // K staging: d block
  const int vkp = tid & 31;          // V staging: kv pair index
  const int vdb = (tid >> 5) * 8;    // V staging: d base 0..56

  const int nt = qt + 1;
  for (int t = 0; t < nt; ++t) {
    const int kv0 = t * 64;
    {
      const u16* kp = kb + basek + (long)(kv0 + skv) * 128 + sdu;
#pragma unroll
      for (int u = 0; u < 4; ++u)
        *(us8*)(Ks + skv * 140 + sdu + 8 * u) = *(const us8*)(kp + 8 * u);
#pragma unroll
      for (int h = 0; h < 2; ++h) {
        const int d0 = vdb + 64 * h;
        const u16* vp = vb + basek + (long)(kv0 + 2 * vkp) * 128 + d0;
        us8 v0 = *(const us8*)vp;
        us8 v1 = *(const us8*)(vp + 128);
#pragma unroll
        for (int j = 0; j < 8; ++j) {
          unsigned pk = (unsigned)v0[j] | ((unsigned)v1[j] << 16);
          *(unsigned*)(Vs + (d0 + j) * 72 + 2 * vkp) = pk;
        }
      }
    }
    __syncthreads();

    // S^T[kv][q] = K . Q^T
    f32x4 accs[4];
#pragma unroll
    for (int i = 0; i < 4; ++i) accs[i] = (f32x4)0.f;
#pragma unroll
    for (int ni = 0; ni < 4; ++ni)
#pragma unroll
      for (int ks = 0; ks < 4; ++ks) {
        bf16x8 kf = *(const bf16x8*)(Ks + (ni * 16 + c) * 140 + 32 * ks + 8 * g);
        accs[ni] = __builtin_amdgcn_mfma_f32_16x16x32_bf16(kf, qf[ks], accs[ni], 0, 0, 0);
      }

    // softmax over kv (per lane: q = q0 + wv*16 + c)
    float sv[4][4];
    float tmax = -1e30f;
    const bool lastt = (t == nt - 1);
#pragma unroll
    for (int ni = 0; ni < 4; ++ni)
#pragma unroll
      for (int r = 0; r < 4; ++r) {
        float s = accs[ni][r] * 0.08838834764831845f;   // 1/sqrt(128)
        if (lastt && (kv0 + ni * 16 + 4 * g + r > q0 + wv * 16 + c)) s = -1e30f;
        sv[ni][r] = s;
        tmax = fmaxf(tmax, s);
      }
    tmax = fmaxf(tmax, __shfl_xor(tmax, 16));
    tmax = fmaxf(tmax, __shfl_xor(tmax, 32));
    const float mn = fmaxf(m, tmax);
    const float alpha = exp2f((m - mn) * L2E);
    m = mn;
    float ps = 0.f;
#pragma unroll
    for (int ni = 0; ni < 4; ++ni) {
      us4 pk;
#pragma unroll
      for (int r = 0; r < 4; ++r) {
        float p = exp2f((sv[ni][r] - mn) * L2E);
        ps += p;
        pk[r] = f2b(p);
      }
      *(us4*)(Ps + (wv * 16 + c) * 72 + ni * 16 + 4 * g) = pk;   // ds_write_b64
    }
    ps += __shfl_xor(ps, 16);
    ps += __shfl_xor(ps, 32);
    l = l * alpha + ps;
    float ar[4];
#pragma unroll
    for (int r = 0; r < 4; ++r) ar[r] = __shfl(alpha, 4 * g + r);
#pragma unroll
    for (int i = 0; i < 8; ++i)
#pragma unroll
      for (int r = 0; r < 4; ++r) acco[i][r] *= ar[r];

    // PV: O[q][d] += P . V   (pf: A-frag of P; vf: B-frag from transposed Vs)
    bf16x8 pf0 = *(const bf16x8*)(Ps + (wv * 16 + c) * 72 + 8 * g);
    bf16x8 pf1 = *(const bf16x8*)(Ps + (wv * 16 + c) * 72 + 32 + 8 * g);
#pragma unroll
    for (int nd = 0; nd < 8; ++nd) {
      bf16x8 vf0 = *(const bf16x8*)(Vs + (16 * nd + c) * 72 + 8 * g);
      bf16x8 vf1 = *(const bf16x8*)(Vs + (16 * nd + c) * 72 + 32 + 8 * g);
      acco[nd] = __builtin_amdgcn_mfma_f32_16x16x32_bf16(pf0, vf0, acco[nd], 0, 0, 0);
      acco[nd] = __builtin_amdgcn_mfma_f32_16x16x32_bf16(pf1, vf1, acco[nd], 0, 0, 0);
    }
    __syncthreads();
  }

  const float inv = 1.f / l;
  float ir[4];
#pragma unroll
  for (int r = 0; r < 4; ++r) ir[r] = __shfl(inv, 4 * g + r);
  const int b = bh >> 4, hh = bh & 15;
#pragma unroll
  for (int r = 0; r < 4; ++r) {
    const long tok = (long)((b << 11) | (q0 + wv * 16 + 4 * g + r));
#pragma unroll
    for (int nd = 0; nd < 8; ++nd)
      a_ws[tok * 2048 + hh * 128 + nd * 16 + c] = acco[nd][r] * ir[r];
  }
}

// ---------------------------------------------------------------------------
// Holographic path, exact time-domain form of irfft(conj(qf)*kf*vf):
//   c[s]    = sum_j k[j] * v[(s-j) & 127]          (circular convolution)
//   holo[t] = (1/128) * sum_tau q[tau] * c[(t+tau) & 127]
// ---------------------------------------------------------------------------
__global__ __launch_bounds__(256, 2)
void holo_kernel(const u16* __restrict__ qb, const u16* __restrict__ kb,
                 const u16* __restrict__ vb, float* __restrict__ h_ws)
{
  __shared__ float qs[4][128], ksd[4][128], vs[4][128], cs[4][128];
  const int tid = threadIdx.x, lane = tid & 63, wv = tid >> 6;
  const long row  = (long)blockIdx.x * 4 + wv;   // bh*2048 + s
  const long base = row * 128;
  qs [wv][lane]      = b2f(qb[base + lane]);
  qs [wv][lane + 64] = b2f(qb[base + lane + 64]);
  ksd[wv][lane]      = b2f(kb[base + lane]);
  ksd[wv][lane + 64] = b2f(kb[base + lane + 64]);
  vs [wv][lane]      = b2f(vb[base + lane]);
  vs [wv][lane + 64] = b2f(vb[base + lane + 64]);
  __syncthreads();
  const int s1 = lane, s2 = lane + 64;
  float c1 = 0.f, c2 = 0.f;
#pragma unroll 4
  for (int j = 0; j < 128; ++j) {
    float kj = ksd[wv][j];
    c1 = fmaf(kj, vs[wv][(s1 - j) & 127], c1);
    c2 = fmaf(kj, vs[wv][(s2 - j) & 127], c2);
  }
  cs[wv][s1] = c1;
  cs[wv][s2] = c2;
  __syncthreads();
  float h1 = 0.f, h2 = 0.f;
#pragma unroll 4
  for (int j = 0; j < 128; ++j) {
    float qj = qs[wv][j];
    h1 = fmaf(qj, cs[wv][(s1 + j) & 127], h1);
    h2 = fmaf(qj, cs[wv][(s2 + j) & 127], h2);
  }
  const int bh = (int)(row >> 11);
  const int s  = (int)(row & 2047);
  const long irow = (long)(((bh >> 4) << 11) | s);
  const int colb  = (bh & 15) * 128;
  h_ws[irow * 2048 + colb + s1] = h1 * 0.0078125f;   // 1/128
  h_ws[irow * 2048 + colb + s2] = h2 * 0.0078125f;
}

// ---------------------------------------------------------------------------
// Fused LayerNorm(a), LayerNorm(h), sigmoid-clip blend; writes into a in-place
// ---------------------------------------------------------------------------
__global__ __launch_bounds__(256)
void ln_blend(float* __restrict__ a, const float* __restrict__ h,
              const float* __restrict__ gate,
              const float* __restrict__ ga, const float* __restrict__ ba,
              const float* __restrict__ gh, const float* __restrict__ bhv)
{
  const int tid = threadIdx.x;
  const long roff = (long)blockIdx.x * 2048 + tid * 8;
  float av[8], hv[8];
  {
    float4 t0 = *(const float4*)(a + roff);
    float4 t1 = *(const float4*)(a + roff + 4);
    av[0]=t0.x; av[1]=t0.y; av[2]=t0.z; av[3]=t0.w;
    av[4]=t1.x; av[5]=t1.y; av[6]=t1.z; av[7]=t1.w;
    float4 t2 = *(const float4*)(h + roff);
    float4 t3 = *(const float4*)(h + roff + 4);
    hv[0]=t2.x; hv[1]=t2.y; hv[2]=t2.z; hv[3]=t2.w;
    hv[4]=t3.x; hv[5]=t3.y; hv[6]=t3.z; hv[7]=t3.w;
  }
  float sa = 0.f, sa2 = 0.f, sh = 0.f, sh2 = 0.f;
#pragma unroll
  for (int i = 0; i < 8; ++i) {
    sa += av[i]; sa2 += av[i] * av[i];
    sh += hv[i]; sh2 += hv[i] * hv[i];
  }
#pragma unroll
  for (int o = 1; o < 64; o <<= 1) {
    sa += __shfl_xor(sa, o); sa2 += __shfl_xor(sa2, o);
    sh += __shfl_xor(sh, o); sh2 += __shfl_xor(sh2, o);
  }
  __shared__ float red[4][4];
  const int wv = tid >> 6;
  if ((tid & 63) == 0) { red[0][wv] = sa; red[1][wv] = sa2; red[2][wv] = sh; red[3][wv] = sh2; }
  __syncthreads();
  sa  = red[0][0] + red[0][1] + red[0][2] + red[0][3];
  sa2 = red[1][0] + red[1][1] + red[1][2] + red[1][3];
  sh  = red[2][0] + red[2][1] + red[2][2] + red[2][3];
  sh2 = red[3][0] + red[3][1] + red[3][2] + red[3][3];
  const float inv = 1.f / 2048.f;
  float ma = sa * inv,  va = sa2 * inv - ma * ma;
  float mh = sh * inv,  vh = sh2 * inv - mh * mh;
  float ra = rsqrtf(va + 1e-5f), rh = rsqrtf(vh + 1e-5f);
  float g = 1.f / (1.f + __expf(-gate[0]));
  g = fminf(fmaxf(g, 0.05f), 0.95f);
  const int j0 = tid * 8;
  float ov[8];
#pragma unroll
  for (int i = 0; i < 8; ++i) {
    float aa = (av[i] - ma) * ra * ga[j0 + i] + ba[j0 + i];
    float hn = (hv[i] - mh) * rh * gh[j0 + i] + bhv[j0 + i];
    ov[i] = (1.f - g) * aa + g * hn;
  }
  float4 o0 = { ov[0], ov[1], ov[2], ov[3] };
  float4 o1 = { ov[4], ov[5], ov[6], ov[7] };
  *(float4*)(a + roff)     = o0;
  *(float4*)(a + roff + 4) = o1;
}

// ---------------------------------------------------------------------------
extern "C" void kernel_launch(void* const* d_in, const int* in_sizes, int n_in,
                              void* d_out, int out_size, void* d_ws, size_t ws_size,
                              hipStream_t stream)
{
  const float* x    = (const float*)d_in[0];
  const float* cosT = (const float*)d_in[1];
  const float* sinT = (const float*)d_in[2];
  const float* qkvw = (const float*)d_in[3];
  const float* outw = (const float*)d_in[4];
  const float* gate = (const float*)d_in[5];
  const float* ga   = (const float*)d_in[6];
  const float* ba   = (const float*)d_in[7];
  const float* gh   = (const float*)d_in[8];
  const float* bhv  = (const float*)d_in[9];
  float* out = (float*)d_out;

  char* w = (char*)d_ws;
  u16* qb = (u16*)w;
  u16* kb = qb + (1u << 23);
  u16* vb = kb + (1u << 23);
  float* a_ws = (float*)(w + 50331648);
  float* h_ws = a_ws + (1u << 23);

  gemm_tn<0><<<dim3(48, 32), 256, 0, stream>>>(x, qkvw, nullptr, qb, kb, vb,
                                               cosT, sinT, 4096, 6144, 2048);
  flash_attn<<<dim3(32, 32), 256, 0, stream>>>(qb, kb, vb, a_ws);
  holo_kernel<<<16384, 256, 0, stream>>>(qb, kb, vb, h_ws);
  ln_blend<<<4096, 256, 0, stream>>>(a_ws, h_ws, gate, ga, ba, gh, bhv);
  gemm_tn<1><<<dim3(16, 32), 256, 0, stream>>>(a_ws, outw, out,
                                               nullptr, nullptr, nullptr,
                                               nullptr, nullptr, 4096, 2048, 2048);
}

// Round 3
// 501.142 us; speedup vs baseline: 1.5659x; 1.1419x over previous
//
#include <hip/hip_runtime.h>

typedef unsigned short u16;
typedef __attribute__((ext_vector_type(4))) unsigned short us4;
typedef __attribute__((ext_vector_type(8))) unsigned short us8;
typedef __attribute__((ext_vector_type(8))) __bf16 bf16x8;
typedef __attribute__((ext_vector_type(4))) float f32x4;

#define L2E 1.4426950408889634f

__device__ __forceinline__ u16 f2b(float f) {
  unsigned u = __builtin_bit_cast(unsigned, f);
  u += 0x7fffu + ((u >> 16) & 1u);          // round-to-nearest-even
  return (u16)(u >> 16);
}
__device__ __forceinline__ float b2f(u16 s) {
  unsigned u = ((unsigned)s) << 16;
  return __builtin_bit_cast(float, u);
}

__device__ __forceinline__ void gload16(const u16* g, const u16* l) {
  __builtin_amdgcn_global_load_lds(
      (const __attribute__((address_space(1))) unsigned*)g,
      (__attribute__((address_space(3))) unsigned*)l, 16, 0, 0);
}

// ---------------------------------------------------------------------------
// f32 -> bf16 convert, 8 elems/thread, exact-multiple sizes (no tail).
// ---------------------------------------------------------------------------
__global__ __launch_bounds__(256)
void convert_bf16(const float* __restrict__ src, u16* __restrict__ dst)
{
  const long i = ((long)blockIdx.x * 256 + threadIdx.x) * 8;
  float4 a = *(const float4*)(src + i);
  float4 b = *(const float4*)(src + i + 4);
  us8 o = { f2b(a.x), f2b(a.y), f2b(a.z), f2b(a.w),
            f2b(b.x), f2b(b.y), f2b(b.z), f2b(b.w) };
  *(us8*)(dst + i) = o;
}

// ---------------------------------------------------------------------------
// bf16 TN GEMM (m97 structure): C[M][N] = A[M][K] @ B[N][K]^T.
// 128x128 tile, BK=32, 4 waves (2x2 of 64x64), mfma 16x16x32 bf16.
// Staging via global_load_lds width=16 (linear LDS dest); bank-conflict-free
// ds_read via involution swizzle q' = q ^ ((row>>1)&3) applied to the GLOBAL
// source address at stage time and to the LDS read address (rule #21).
// MODE 0: RoPE + scatter to per-head q/k/v bf16 (QKV GEMM).
// MODE 1: plain f32 store (OUT GEMM).
// ---------------------------------------------------------------------------
template<int MODE>
__global__ __launch_bounds__(256, 3)
void gemm_bf16(const u16* __restrict__ A, const u16* __restrict__ Bm,
               float* __restrict__ Cout,
               u16* __restrict__ qb, u16* __restrict__ kb, u16* __restrict__ vb,
               const float* __restrict__ cosT, const float* __restrict__ sinT,
               int M, int N, int K)
{
  __shared__ u16 As[128 * 32];
  __shared__ u16 Bs[128 * 32];
  const int tid  = threadIdx.x;
  const int lane = tid & 63;
  const int wid  = tid >> 6;
  const int c    = lane & 15;
  const int g    = lane >> 4;

  // XCD-bijective swizzle (gridDim.x % 8 == 0 for both uses)
  const int cpx  = gridDim.x >> 3;
  const int flat = blockIdx.x;
  const int swz  = (flat & 7) * cpx + (flat >> 3);
  const int ntx  = N >> 7;
  const int m0 = (swz / ntx) * 128;
  const int n0 = (swz % ntx) * 128;
  const int wm = (wid >> 1) * 64;
  const int wn = (wid & 1) * 64;

  f32x4 acc[4][4];
#pragma unroll
  for (int i = 0; i < 4; ++i)
#pragma unroll
    for (int j = 0; j < 4; ++j) acc[i][j] = (f32x4)0.f;

  // ---- staging addresses (k0-invariant except +k0) ----
  const int srow = lane >> 2;                         // 0..15 in chunk
  const int scol = ((lane & 3) ^ ((srow >> 1) & 3)) << 3;   // swizzled src col
  const u16* Ag0 = A  + (long)(m0 + wid * 32 + srow) * K + scol;
  const u16* Ag1 = Ag0 + (long)16 * K;
  const u16* Bg0 = Bm + (long)(n0 + wid * 32 + srow) * K + scol;
  const u16* Bg1 = Bg0 + (long)16 * K;
  const u16* la0 = &As[(wid * 32) * 32];
  const u16* la1 = &As[(wid * 32 + 16) * 32];
  const u16* lb0 = &Bs[(wid * 32) * 32];
  const u16* lb1 = &Bs[(wid * 32 + 16) * 32];

  // ---- fragment LDS offsets (k0-invariant) ----
  int aoff[4], boff[4];
#pragma unroll
  for (int mi = 0; mi < 4; ++mi) {
    int rl = wm + mi * 16 + c;
    aoff[mi] = rl * 32 + ((g ^ ((rl >> 1) & 3)) << 3);
  }
#pragma unroll
  for (int ni = 0; ni < 4; ++ni) {
    int rl = wn + ni * 16 + c;
    boff[ni] = rl * 32 + ((g ^ ((rl >> 1) & 3)) << 3);
  }

  for (int k0 = 0; k0 < K; k0 += 32) {
    gload16(Ag0 + k0, la0);
    gload16(Ag1 + k0, la1);
    gload16(Bg0 + k0, lb0);
    gload16(Bg1 + k0, lb1);
    __syncthreads();

    bf16x8 af[4], bfr[4];
#pragma unroll
    for (int mi = 0; mi < 4; ++mi) af[mi]  = *(const bf16x8*)(As + aoff[mi]);
#pragma unroll
    for (int ni = 0; ni < 4; ++ni) bfr[ni] = *(const bf16x8*)(Bs + boff[ni]);
#pragma unroll
    for (int mi = 0; mi < 4; ++mi)
#pragma unroll
      for (int ni = 0; ni < 4; ++ni)
        acc[mi][ni] = __builtin_amdgcn_mfma_f32_16x16x32_bf16(af[mi], bfr[ni], acc[mi][ni], 0, 0, 0);
    __syncthreads();
  }

  if (MODE == 0) {
    // whole 128-col tile is one (w, head) slice: n = w*2048 + h*128 + d
    const int w  = n0 >> 11;
    const int hh = (n0 >> 7) & 15;
#pragma unroll
    for (int mi = 0; mi < 4; ++mi) {
      const int rowb = m0 + wm + mi * 16 + g * 4;
#pragma unroll
      for (int ni = 0; ni < 4; ++ni) {
        const int d = wn + ni * 16 + c;
#pragma unroll
        for (int r = 0; r < 4; ++r) {
          float val = acc[mi][ni][r];
          float oth = __shfl_xor(val, 1);   // RoPE partner (d^1), uniform control
          const int tok = rowb + r;
          const int s   = tok & 2047;
          const long idx = ((long)(((tok >> 11) << 4) | hh) * 2048 + s) * 128 + d;
          if (w == 2) {
            vb[idx] = f2b(val);
          } else {
            float cc = cosT[s * 64 + (d >> 1)];
            float sn = sinT[s * 64 + (d >> 1)];
            float res = (d & 1) ? (oth * sn + val * cc) : (val * cc - oth * sn);
            ((w == 0) ? qb : kb)[idx] = f2b(res);
          }
        }
      }
    }
  } else {
#pragma unroll
    for (int mi = 0; mi < 4; ++mi) {
      const int rowb = m0 + wm + mi * 16 + g * 4;
#pragma unroll
      for (int ni = 0; ni < 4; ++ni) {
        const int col = n0 + wn + ni * 16 + c;
#pragma unroll
        for (int r = 0; r < 4; ++r)
          Cout[(long)(rowb + r) * N + col] = acc[mi][ni][r];
      }
    }
  }
}

// ---------------------------------------------------------------------------
// Causal flash attention v2 — swapped-operand S^T = mfma(K, Q).
// ---------------------------------------------------------------------------
__global__ __launch_bounds__(256, 3)
void flash_attn(const u16* __restrict__ qb, const u16* __restrict__ kb,
                const u16* __restrict__ vb, float* __restrict__ a_ws)
{
  __shared__ u16 Ks[64 * 140];   // [kv][d]   stride 140
  __shared__ u16 Vs[128 * 72];   // [d][kv]   stride 72 (transposed)
  __shared__ u16 Ps[64 * 72];    // [qrow][kv] stride 72
  const int tid  = threadIdx.x;
  const int lane = tid & 63;
  const int wv   = tid >> 6;
  const int c    = lane & 15;
  const int g    = lane >> 4;
  const int bh = blockIdx.x;
  const int qt = 31 - blockIdx.y;          // biggest blocks dispatch first
  const int q0 = qt * 64;
  const long basek = (long)bh * 2048 * 128;

  bf16x8 qf[4];
  {
    const u16* qptr = qb + basek + (long)(q0 + wv * 16 + c) * 128 + 8 * g;
#pragma unroll
    for (int ks = 0; ks < 4; ++ks) qf[ks] = *(const bf16x8*)(qptr + 32 * ks);
  }
  f32x4 acco[8];
#pragma unroll
  for (int i = 0; i < 8; ++i) acco[i] = (f32x4)0.f;
  float m = -1e30f, l = 0.f;

  const int skv = tid >> 2;
  const int sdu = (tid & 3) * 32;
  const int vkp = tid & 31;
  const int vdb = (tid >> 5) * 8;

  const int nt = qt + 1;
  for (int t = 0; t < nt; ++t) {
    const int kv0 = t * 64;
    {
      const u16* kp = kb + basek + (long)(kv0 + skv) * 128 + sdu;
#pragma unroll
      for (int u = 0; u < 4; ++u)
        *(us8*)(Ks + skv * 140 + sdu + 8 * u) = *(const us8*)(kp + 8 * u);
#pragma unroll
      for (int h = 0; h < 2; ++h) {
        const int d0 = vdb + 64 * h;
        const u16* vp = vb + basek + (long)(kv0 + 2 * vkp) * 128 + d0;
        us8 v0 = *(const us8*)vp;
        us8 v1 = *(const us8*)(vp + 128);
#pragma unroll
        for (int j = 0; j < 8; ++j) {
          unsigned pk = (unsigned)v0[j] | ((unsigned)v1[j] << 16);
          *(unsigned*)(Vs + (d0 + j) * 72 + 2 * vkp) = pk;
        }
      }
    }
    __syncthreads();

    f32x4 accs[4];
#pragma unroll
    for (int i = 0; i < 4; ++i) accs[i] = (f32x4)0.f;
#pragma unroll
    for (int ni = 0; ni < 4; ++ni)
#pragma unroll
      for (int ks = 0; ks < 4; ++ks) {
        bf16x8 kf = *(const bf16x8*)(Ks + (ni * 16 + c) * 140 + 32 * ks + 8 * g);
        accs[ni] = __builtin_amdgcn_mfma_f32_16x16x32_bf16(kf, qf[ks], accs[ni], 0, 0, 0);
      }

    float sv[4][4];
    float tmax = -1e30f;
    const bool lastt = (t == nt - 1);
#pragma unroll
    for (int ni = 0; ni < 4; ++ni)
#pragma unroll
      for (int r = 0; r < 4; ++r) {
        float s = accs[ni][r] * 0.08838834764831845f;
        if (lastt && (kv0 + ni * 16 + 4 * g + r > q0 + wv * 16 + c)) s = -1e30f;
        sv[ni][r] = s;
        tmax = fmaxf(tmax, s);
      }
    tmax = fmaxf(tmax, __shfl_xor(tmax, 16));
    tmax = fmaxf(tmax, __shfl_xor(tmax, 32));
    const float mn = fmaxf(m, tmax);
    const float alpha = exp2f((m - mn) * L2E);
    m = mn;
    float ps = 0.f;
#pragma unroll
    for (int ni = 0; ni < 4; ++ni) {
      us4 pk;
#pragma unroll
      for (int r = 0; r < 4; ++r) {
        float p = exp2f((sv[ni][r] - mn) * L2E);
        ps += p;
        pk[r] = f2b(p);
      }
      *(us4*)(Ps + (wv * 16 + c) * 72 + ni * 16 + 4 * g) = pk;
    }
    ps += __shfl_xor(ps, 16);
    ps += __shfl_xor(ps, 32);
    l = l * alpha + ps;
    float ar[4];
#pragma unroll
    for (int r = 0; r < 4; ++r) ar[r] = __shfl(alpha, 4 * g + r);
#pragma unroll
    for (int i = 0; i < 8; ++i)
#pragma unroll
      for (int r = 0; r < 4; ++r) acco[i][r] *= ar[r];

    bf16x8 pf0 = *(const bf16x8*)(Ps + (wv * 16 + c) * 72 + 8 * g);
    bf16x8 pf1 = *(const bf16x8*)(Ps + (wv * 16 + c) * 72 + 32 + 8 * g);
#pragma unroll
    for (int nd = 0; nd < 8; ++nd) {
      bf16x8 vf0 = *(const bf16x8*)(Vs + (16 * nd + c) * 72 + 8 * g);
      bf16x8 vf1 = *(const bf16x8*)(Vs + (16 * nd + c) * 72 + 32 + 8 * g);
      acco[nd] = __builtin_amdgcn_mfma_f32_16x16x32_bf16(pf0, vf0, acco[nd], 0, 0, 0);
      acco[nd] = __builtin_amdgcn_mfma_f32_16x16x32_bf16(pf1, vf1, acco[nd], 0, 0, 0);
    }
    __syncthreads();
  }

  const float inv = 1.f / l;
  float ir[4];
#pragma unroll
  for (int r = 0; r < 4; ++r) ir[r] = __shfl(inv, 4 * g + r);
  const int b = bh >> 4, hh = bh & 15;
#pragma unroll
  for (int r = 0; r < 4; ++r) {
    const long tok = (long)((b << 11) | (q0 + wv * 16 + 4 * g + r));
#pragma unroll
    for (int nd = 0; nd < 8; ++nd)
      a_ws[tok * 2048 + hh * 128 + nd * 16 + c] = acco[nd][r] * ir[r];
  }
}

// ---------------------------------------------------------------------------
// Holographic path (exact time-domain irfft(conj(qf)*kf*vf)).
// ---------------------------------------------------------------------------
__global__ __launch_bounds__(256, 2)
void holo_kernel(const u16* __restrict__ qb, const u16* __restrict__ kb,
                 const u16* __restrict__ vb, float* __restrict__ h_ws)
{
  __shared__ float qs[4][128], ksd[4][128], vs[4][128], cs[4][128];
  const int tid = threadIdx.x, lane = tid & 63, wv = tid >> 6;
  const long row  = (long)blockIdx.x * 4 + wv;
  const long base = row * 128;
  qs [wv][lane]      = b2f(qb[base + lane]);
  qs [wv][lane + 64] = b2f(qb[base + lane + 64]);
  ksd[wv][lane]      = b2f(kb[base + lane]);
  ksd[wv][lane + 64] = b2f(kb[base + lane + 64]);
  vs [wv][lane]      = b2f(vb[base + lane]);
  vs [wv][lane + 64] = b2f(vb[base + lane + 64]);
  __syncthreads();
  const int s1 = lane, s2 = lane + 64;
  float c1 = 0.f, c2 = 0.f;
#pragma unroll 4
  for (int j = 0; j < 128; ++j) {
    float kj = ksd[wv][j];
    c1 = fmaf(kj, vs[wv][(s1 - j) & 127], c1);
    c2 = fmaf(kj, vs[wv][(s2 - j) & 127], c2);
  }
  cs[wv][s1] = c1;
  cs[wv][s2] = c2;
  __syncthreads();
  float h1 = 0.f, h2 = 0.f;
#pragma unroll 4
  for (int j = 0; j < 128; ++j) {
    float qj = qs[wv][j];
    h1 = fmaf(qj, cs[wv][(s1 + j) & 127], h1);
    h2 = fmaf(qj, cs[wv][(s2 + j) & 127], h2);
  }
  const int bh = (int)(row >> 11);
  const int s  = (int)(row & 2047);
  const long irow = (long)(((bh >> 4) << 11) | s);
  const int colb  = (bh & 15) * 128;
  h_ws[irow * 2048 + colb + s1] = h1 * 0.0078125f;
  h_ws[irow * 2048 + colb + s2] = h2 * 0.0078125f;
}

// ---------------------------------------------------------------------------
// Fused LayerNorm(a), LayerNorm(h), blend -> bf16 output for the OUT GEMM.
// ---------------------------------------------------------------------------
__global__ __launch_bounds__(256)
void ln_blend(const float* __restrict__ a, const float* __restrict__ h,
              u16* __restrict__ ab,
              const float* __restrict__ gate,
              const float* __restrict__ ga, const float* __restrict__ ba,
              const float* __restrict__ gh, const float* __restrict__ bhv)
{
  const int tid = threadIdx.x;
  const long roff = (long)blockIdx.x * 2048 + tid * 8;
  float av[8], hv[8];
  {
    float4 t0 = *(const float4*)(a + roff);
    float4 t1 = *(const float4*)(a + roff + 4);
    av[0]=t0.x; av[1]=t0.y; av[2]=t0.z; av[3]=t0.w;
    av[4]=t1.x; av[5]=t1.y; av[6]=t1.z; av[7]=t1.w;
    float4 t2 = *(const float4*)(h + roff);
    float4 t3 = *(const float4*)(h + roff + 4);
    hv[0]=t2.x; hv[1]=t2.y; hv[2]=t2.z; hv[3]=t2.w;
    hv[4]=t3.x; hv[5]=t3.y; hv[6]=t3.z; hv[7]=t3.w;
  }
  float sa = 0.f, sa2 = 0.f, sh = 0.f, sh2 = 0.f;
#pragma unroll
  for (int i = 0; i < 8; ++i) {
    sa += av[i]; sa2 += av[i] * av[i];
    sh += hv[i]; sh2 += hv[i] * hv[i];
  }
#pragma unroll
  for (int o = 1; o < 64; o <<= 1) {
    sa += __shfl_xor(sa, o); sa2 += __shfl_xor(sa2, o);
    sh += __shfl_xor(sh, o); sh2 += __shfl_xor(sh2, o);
  }
  __shared__ float red[4][4];
  const int wv = tid >> 6;
  if ((tid & 63) == 0) { red[0][wv] = sa; red[1][wv] = sa2; red[2][wv] = sh; red[3][wv] = sh2; }
  __syncthreads();
  sa  = red[0][0] + red[0][1] + red[0][2] + red[0][3];
  sa2 = red[1][0] + red[1][1] + red[1][2] + red[1][3];
  sh  = red[2][0] + red[2][1] + red[2][2] + red[2][3];
  sh2 = red[3][0] + red[3][1] + red[3][2] + red[3][3];
  const float inv = 1.f / 2048.f;
  float ma = sa * inv,  va = sa2 * inv - ma * ma;
  float mh = sh * inv,  vh = sh2 * inv - mh * mh;
  float ra = rsqrtf(va + 1e-5f), rh = rsqrtf(vh + 1e-5f);
  float g = 1.f / (1.f + __expf(-gate[0]));
  g = fminf(fmaxf(g, 0.05f), 0.95f);
  const int j0 = tid * 8;
  us8 o;
#pragma unroll
  for (int i = 0; i < 8; ++i) {
    float aa = (av[i] - ma) * ra * ga[j0 + i] + ba[j0 + i];
    float hn = (hv[i] - mh) * rh * gh[j0 + i] + bhv[j0 + i];
    o[i] = f2b((1.f - g) * aa + g * hn);
  }
  *(us8*)(ab + roff) = o;
}

// ---------------------------------------------------------------------------
extern "C" void kernel_launch(void* const* d_in, const int* in_sizes, int n_in,
                              void* d_out, int out_size, void* d_ws, size_t ws_size,
                              hipStream_t stream)
{
  const float* x    = (const float*)d_in[0];
  const float* cosT = (const float*)d_in[1];
  const float* sinT = (const float*)d_in[2];
  const float* qkvw = (const float*)d_in[3];
  const float* outw = (const float*)d_in[4];
  const float* gate = (const float*)d_in[5];
  const float* ga   = (const float*)d_in[6];
  const float* ba   = (const float*)d_in[7];
  const float* gh   = (const float*)d_in[8];
  const float* bhv  = (const float*)d_in[9];
  float* out = (float*)d_out;

  // workspace (112 MiB, proven safe):
  //   qb [0,16M)  kb [16,32M)  vb [32,48M)
  //   a_ws f32 [48,80M)   (xb bf16 aliases [48,64M) before flash)
  //   h_ws f32 [80,112M)  (wb bf16 aliases [80,104M) before holo)
  //   ob aliases kb (after holo), ab aliases qb (after holo)
  char* w = (char*)d_ws;
  u16* qb = (u16*)w;
  u16* kb = (u16*)(w + (16u << 20));
  u16* vb = (u16*)(w + (32u << 20));
  float* a_ws = (float*)(w + (48u << 20));
  float* h_ws = (float*)(w + (80u << 20));
  u16* xb = (u16*)(w + (48u << 20));
  u16* wb = (u16*)(w + (80u << 20));
  u16* ob = kb;
  u16* ab = qb;

  convert_bf16<<<4096, 256, 0, stream>>>(x,    xb);   //  8.4M elems
  convert_bf16<<<6144, 256, 0, stream>>>(qkvw, wb);   // 12.6M elems
  gemm_bf16<0><<<1536, 256, 0, stream>>>(xb, wb, nullptr, qb, kb, vb,
                                         cosT, sinT, 4096, 6144, 2048);
  flash_attn<<<dim3(32, 32), 256, 0, stream>>>(qb, kb, vb, a_ws);
  holo_kernel<<<16384, 256, 0, stream>>>(qb, kb, vb, h_ws);
  convert_bf16<<<2048, 256, 0, stream>>>(outw, ob);   //  4.2M elems
  ln_blend<<<4096, 256, 0, stream>>>(a_ws, h_ws, ab, gate, ga, ba, gh, bhv);
  gemm_bf16<1><<<512, 256, 0, stream>>>(ab, ob, out, nullptr, nullptr, nullptr,
                                        nullptr, nullptr, 4096, 2048, 2048);
}

// Round 4
// 367.863 us; speedup vs baseline: 2.1332x; 1.3623x over previous
//
#include <hip/hip_runtime.h>

typedef unsigned short u16;
typedef __attribute__((ext_vector_type(4))) unsigned short us4;
typedef __attribute__((ext_vector_type(8))) unsigned short us8;
typedef __attribute__((ext_vector_type(8))) __bf16 bf16x8;
typedef __attribute__((ext_vector_type(4))) float f32x4;

#define L2E 1.4426950408889634f
#define RSQ128 0.08838834764831845f

__device__ __forceinline__ u16 f2b(float f) {
  unsigned u = __builtin_bit_cast(unsigned, f);
  u += 0x7fffu + ((u >> 16) & 1u);          // round-to-nearest-even
  return (u16)(u >> 16);
}
__device__ __forceinline__ float b2f(u16 s) {
  unsigned u = ((unsigned)s) << 16;
  return __builtin_bit_cast(float, u);
}

__device__ __forceinline__ void gload16(const u16* g, const u16* l) {
  __builtin_amdgcn_global_load_lds(
      (const __attribute__((address_space(1))) unsigned*)g,
      (__attribute__((address_space(3))) unsigned*)l, 16, 0, 0);
}

// ---------------------------------------------------------------------------
// f32 -> bf16 convert, 8 elems/thread.
// ---------------------------------------------------------------------------
__global__ __launch_bounds__(256)
void convert_bf16(const float* __restrict__ src, u16* __restrict__ dst)
{
  const long i = ((long)blockIdx.x * 256 + threadIdx.x) * 8;
  float4 a = *(const float4*)(src + i);
  float4 b = *(const float4*)(src + i + 4);
  us8 o = { f2b(a.x), f2b(a.y), f2b(a.z), f2b(a.w),
            f2b(b.x), f2b(b.y), f2b(b.z), f2b(b.w) };
  *(us8*)(dst + i) = o;
}

// ---------------------------------------------------------------------------
// DFT tables (bf16).
// Fmat [144][128]: fc=2f -> cos(2pi f d/128)/sqrt(128); fc=2f+1 -> -sin(..)/sqrt(128)
//                  (f=0..64 -> fc 0..129); fc>=130 -> 0.
// Cmat [128][160]: row t, col fc: fc=2f even: (f==0?1 : f==64?(-1)^t : 2cos(2pi f t/128))/sqrt(128)
//                  fc=2f+1 odd: (f==0||f==64)?0 : -2 sin(2pi f t/128)/sqrt(128); fc>=130 -> 0.
// ---------------------------------------------------------------------------
__global__ __launch_bounds__(256)
void init_tables(u16* __restrict__ Fm, u16* __restrict__ Cm)
{
  const int i = blockIdx.x * 256 + threadIdx.x;
  const float w0 = 6.283185307179586f / 128.f;
  if (i < 144 * 128) {
    const int fc = i >> 7, d = i & 127;
    float v = 0.f;
    if (fc < 130) {
      const int f = fc >> 1;
      const float ang = (float)((f * d) & 127) * w0;
      v = ((fc & 1) == 0 ? cosf(ang) : -sinf(ang)) * RSQ128;
    }
    Fm[i] = f2b(v);
  } else {
    const int j = i - 144 * 128;
    const int t = j / 160, fc = j % 160;
    float v = 0.f;
    if (fc < 130) {
      const int f = fc >> 1;
      if ((fc & 1) == 0) {
        if (f == 0)       v = RSQ128;
        else if (f == 64) v = (t & 1) ? -RSQ128 : RSQ128;
        else              v = 2.f * cosf((float)((f * t) & 127) * w0) * RSQ128;
      } else {
        if (f != 0 && f != 64)
          v = -2.f * sinf((float)((f * t) & 127) * w0) * RSQ128;
      }
    }
    Cm[j] = f2b(v);
  }
}

// ---------------------------------------------------------------------------
// bf16 TN GEMM (m97 structure): C[M][N] = A[M][K] @ B[N][K]^T.
// MODE 0: RoPE + scatter to per-head q/k/v bf16 (QKV GEMM).
// MODE 1: plain f32 store (OUT GEMM).
// MODE 2: holo inverse-DFT epilogue -> bf16 scatter to token layout (via qb).
// ---------------------------------------------------------------------------
template<int MODE>
__global__ __launch_bounds__(256, 3)
void gemm_bf16(const u16* __restrict__ A, const u16* __restrict__ Bm,
               float* __restrict__ Cout,
               u16* __restrict__ qb, u16* __restrict__ kb, u16* __restrict__ vb,
               const float* __restrict__ cosT, const float* __restrict__ sinT,
               int M, int N, int K)
{
  __shared__ u16 As[128 * 32];
  __shared__ u16 Bs[128 * 32];
  const int tid  = threadIdx.x;
  const int lane = tid & 63;
  const int wid  = tid >> 6;
  const int c    = lane & 15;
  const int g    = lane >> 4;

  const int cpx  = gridDim.x >> 3;
  const int flat = blockIdx.x;
  const int swz  = (flat & 7) * cpx + (flat >> 3);
  const int ntx  = N >> 7;
  const int m0 = (swz / ntx) * 128;
  const int n0 = (swz % ntx) * 128;
  const int wm = (wid >> 1) * 64;
  const int wn = (wid & 1) * 64;

  f32x4 acc[4][4];
#pragma unroll
  for (int i = 0; i < 4; ++i)
#pragma unroll
    for (int j = 0; j < 4; ++j) acc[i][j] = (f32x4)0.f;

  const int srow = lane >> 2;
  const int scol = ((lane & 3) ^ ((srow >> 1) & 3)) << 3;
  const u16* Ag0 = A  + (long)(m0 + wid * 32 + srow) * K + scol;
  const u16* Ag1 = Ag0 + (long)16 * K;
  const u16* Bg0 = Bm + (long)(n0 + wid * 32 + srow) * K + scol;
  const u16* Bg1 = Bg0 + (long)16 * K;
  const u16* la0 = &As[(wid * 32) * 32];
  const u16* la1 = &As[(wid * 32 + 16) * 32];
  const u16* lb0 = &Bs[(wid * 32) * 32];
  const u16* lb1 = &Bs[(wid * 32 + 16) * 32];

  int aoff[4], boff[4];
#pragma unroll
  for (int mi = 0; mi < 4; ++mi) {
    int rl = wm + mi * 16 + c;
    aoff[mi] = rl * 32 + ((g ^ ((rl >> 1) & 3)) << 3);
  }
#pragma unroll
  for (int ni = 0; ni < 4; ++ni) {
    int rl = wn + ni * 16 + c;
    boff[ni] = rl * 32 + ((g ^ ((rl >> 1) & 3)) << 3);
  }

  for (int k0 = 0; k0 < K; k0 += 32) {
    gload16(Ag0 + k0, la0);
    gload16(Ag1 + k0, la1);
    gload16(Bg0 + k0, lb0);
    gload16(Bg1 + k0, lb1);
    __syncthreads();

    bf16x8 af[4], bfr[4];
#pragma unroll
    for (int mi = 0; mi < 4; ++mi) af[mi]  = *(const bf16x8*)(As + aoff[mi]);
#pragma unroll
    for (int ni = 0; ni < 4; ++ni) bfr[ni] = *(const bf16x8*)(Bs + boff[ni]);
#pragma unroll
    for (int mi = 0; mi < 4; ++mi)
#pragma unroll
      for (int ni = 0; ni < 4; ++ni)
        acc[mi][ni] = __builtin_amdgcn_mfma_f32_16x16x32_bf16(af[mi], bfr[ni], acc[mi][ni], 0, 0, 0);
    __syncthreads();
  }

  if (MODE == 0) {
    const int w  = n0 >> 11;
    const int hh = (n0 >> 7) & 15;
#pragma unroll
    for (int mi = 0; mi < 4; ++mi) {
      const int rowb = m0 + wm + mi * 16 + g * 4;
#pragma unroll
      for (int ni = 0; ni < 4; ++ni) {
        const int d = wn + ni * 16 + c;
#pragma unroll
        for (int r = 0; r < 4; ++r) {
          float val = acc[mi][ni][r];
          float oth = __shfl_xor(val, 1);
          const int tok = rowb + r;
          const int s   = tok & 2047;
          const long idx = ((long)(((tok >> 11) << 4) | hh) * 2048 + s) * 128 + d;
          if (w == 2) {
            vb[idx] = f2b(val);
          } else {
            float cc = cosT[s * 64 + (d >> 1)];
            float sn = sinT[s * 64 + (d >> 1)];
            float res = (d & 1) ? (oth * sn + val * cc) : (val * cc - oth * sn);
            ((w == 0) ? qb : kb)[idx] = f2b(res);
          }
        }
      }
    }
  } else if (MODE == 1) {
#pragma unroll
    for (int mi = 0; mi < 4; ++mi) {
      const int rowb = m0 + wm + mi * 16 + g * 4;
#pragma unroll
      for (int ni = 0; ni < 4; ++ni) {
        const int col = n0 + wn + ni * 16 + c;
#pragma unroll
        for (int r = 0; r < 4; ++r)
          Cout[(long)(rowb + r) * N + col] = acc[mi][ni][r];
      }
    }
  } else {
    // MODE 2: rows are (bh*2048+s); write bf16 holo into token layout via qb
#pragma unroll
    for (int mi = 0; mi < 4; ++mi) {
      const int rowb = m0 + wm + mi * 16 + g * 4;
#pragma unroll
      for (int ni = 0; ni < 4; ++ni) {
        const int t = wn + ni * 16 + c;   // 0..127
#pragma unroll
        for (int r = 0; r < 4; ++r) {
          const int row = rowb + r;
          const int bh = row >> 11, s = row & 2047;
          const long addr = ((long)(((bh >> 4) << 11) | s) << 11) + ((bh & 15) << 7) + t;
          qb[addr] = f2b(acc[mi][ni][r]);
        }
      }
    }
  }
}

// ---------------------------------------------------------------------------
// Holographic forward: Qf/Kf/Vf = rows @ F (fused 3x GEMM, shared B), then
// P = conj(Qf)*Kf*Vf elementwise (re/im = adjacent lanes -> shfl_xor(1)),
// write P bf16 [65536][160] (cols 130..159 zero).
// 512 thr / 8 waves, wave = 16 rows; F staged XOR-swizzled in LDS.
// ---------------------------------------------------------------------------
__global__ __launch_bounds__(512, 1)
void holo_fwd(const u16* __restrict__ qb, const u16* __restrict__ kb,
              const u16* __restrict__ vb, const u16* __restrict__ Fm,
              u16* __restrict__ P)
{
  __shared__ u16 Fs[144 * 128];
  const int tid = threadIdx.x, lane = tid & 63, wv = tid >> 6;
  const int c = lane & 15, g = lane >> 4;
  const long row0 = (long)blockIdx.x * 128;

  // stage F with row-XOR swizzle: byte ^= (fc&7)<<4
  for (int i = tid; i < 144 * 16; i += 512) {
    const int fc = i >> 4, d8 = (i & 15) << 3;
    us8 v = *(const us8*)(Fm + fc * 128 + d8);
    *(us8*)((char*)Fs + ((fc * 256 + d8 * 2) ^ ((fc & 7) << 4))) = v;
  }

  // A-fragments (q,k,v rows) straight from global
  const long ar = row0 + wv * 16 + c;
  bf16x8 aq[4], ak[4], av[4];
#pragma unroll
  for (int ks = 0; ks < 4; ++ks) {
    aq[ks] = *(const bf16x8*)(qb + ar * 128 + 32 * ks + 8 * g);
    ak[ks] = *(const bf16x8*)(kb + ar * 128 + 32 * ks + 8 * g);
    av[ks] = *(const bf16x8*)(vb + ar * 128 + 32 * ks + 8 * g);
  }
  __syncthreads();

  f32x4 accq[9], acck[9], accv[9];
#pragma unroll
  for (int nt = 0; nt < 9; ++nt) {
    accq[nt] = (f32x4)0.f; acck[nt] = (f32x4)0.f; accv[nt] = (f32x4)0.f;
  }
#pragma unroll
  for (int nt = 0; nt < 9; ++nt) {
    const int fc = nt * 16 + c;
    const int sw = (fc & 7) << 4;
#pragma unroll
    for (int ks = 0; ks < 4; ++ks) {
      bf16x8 bf = *(const bf16x8*)((char*)Fs + ((fc * 256 + (32 * ks + 8 * g) * 2) ^ sw));
      accq[nt] = __builtin_amdgcn_mfma_f32_16x16x32_bf16(aq[ks], bf, accq[nt], 0, 0, 0);
      acck[nt] = __builtin_amdgcn_mfma_f32_16x16x32_bf16(ak[ks], bf, acck[nt], 0, 0, 0);
      accv[nt] = __builtin_amdgcn_mfma_f32_16x16x32_bf16(av[ks], bf, accv[nt], 0, 0, 0);
    }
  }

  // product + store: lane holds rows (4g+r), col fc=16nt+c; even fc=re, odd=im
  const bool even = ((c & 1) == 0);
  const long prow = row0 + wv * 16 + 4 * g;
#pragma unroll
  for (int nt = 0; nt < 9; ++nt) {
#pragma unroll
    for (int r = 0; r < 4; ++r) {
      float q = accq[nt][r], k = acck[nt][r], v = accv[nt][r];
      float xq = __shfl_xor(q, 1), xk = __shfl_xor(k, 1), xv = __shfl_xor(v, 1);
      float bc = even ? (k * v - xk * xv) : (xk * v + k * xv);
      float xbc = __shfl_xor(bc, 1);
      float p = even ? (q * bc + xq * xbc) : (xq * bc - q * xbc);
      P[(prow + r) * 160 + nt * 16 + c] = f2b(p);
    }
  }
#pragma unroll
  for (int r = 0; r < 4; ++r) P[(prow + r) * 160 + 144 + c] = 0;   // pad
}

// ---------------------------------------------------------------------------
// Causal flash attention (swapped-operand), bf16 output.
// ---------------------------------------------------------------------------
__global__ __launch_bounds__(256, 3)
void flash_attn(const u16* __restrict__ qb, const u16* __restrict__ kb,
                const u16* __restrict__ vb, u16* __restrict__ ab16)
{
  __shared__ u16 Ks[64 * 140];
  __shared__ u16 Vs[128 * 72];
  __shared__ u16 Ps[64 * 72];
  const int tid  = threadIdx.x;
  const int lane = tid & 63;
  const int wv   = tid >> 6;
  const int c    = lane & 15;
  const int g    = lane >> 4;
  const int bh = blockIdx.x;
  const int qt = 31 - blockIdx.y;
  const int q0 = qt * 64;
  const long basek = (long)bh * 2048 * 128;

  bf16x8 qf[4];
  {
    const u16* qptr = qb + basek + (long)(q0 + wv * 16 + c) * 128 + 8 * g;
#pragma unroll
    for (int ks = 0; ks < 4; ++ks) qf[ks] = *(const bf16x8*)(qptr + 32 * ks);
  }
  f32x4 acco[8];
#pragma unroll
  for (int i = 0; i < 8; ++i) acco[i] = (f32x4)0.f;
  float m = -1e30f, l = 0.f;

  const int skv = tid >> 2;
  const int sdu = (tid & 3) * 32;
  const int vkp = tid & 31;
  const int vdb = (tid >> 5) * 8;

  const int nt = qt + 1;
  for (int t = 0; t < nt; ++t) {
    const int kv0 = t * 64;
    {
      const u16* kp = kb + basek + (long)(kv0 + skv) * 128 + sdu;
#pragma unroll
      for (int u = 0; u < 4; ++u)
        *(us8*)(Ks + skv * 140 + sdu + 8 * u) = *(const us8*)(kp + 8 * u);
#pragma unroll
      for (int h = 0; h < 2; ++h) {
        const int d0 = vdb + 64 * h;
        const u16* vp = vb + basek + (long)(kv0 + 2 * vkp) * 128 + d0;
        us8 v0 = *(const us8*)vp;
        us8 v1 = *(const us8*)(vp + 128);
#pragma unroll
        for (int j = 0; j < 8; ++j) {
          unsigned pk = (unsigned)v0[j] | ((unsigned)v1[j] << 16);
          *(unsigned*)(Vs + (d0 + j) * 72 + 2 * vkp) = pk;
        }
      }
    }
    __syncthreads();

    f32x4 accs[4];
#pragma unroll
    for (int i = 0; i < 4; ++i) accs[i] = (f32x4)0.f;
#pragma unroll
    for (int ni = 0; ni < 4; ++ni)
#pragma unroll
      for (int ks = 0; ks < 4; ++ks) {
        bf16x8 kf = *(const bf16x8*)(Ks + (ni * 16 + c) * 140 + 32 * ks + 8 * g);
        accs[ni] = __builtin_amdgcn_mfma_f32_16x16x32_bf16(kf, qf[ks], accs[ni], 0, 0, 0);
      }

    float sv[4][4];
    float tmax = -1e30f;
    const bool lastt = (t == nt - 1);
#pragma unroll
    for (int ni = 0; ni < 4; ++ni)
#pragma unroll
      for (int r = 0; r < 4; ++r) {
        float s = accs[ni][r] * RSQ128;
        if (lastt && (kv0 + ni * 16 + 4 * g + r > q0 + wv * 16 + c)) s = -1e30f;
        sv[ni][r] = s;
        tmax = fmaxf(tmax, s);
      }
    tmax = fmaxf(tmax, __shfl_xor(tmax, 16));
    tmax = fmaxf(tmax, __shfl_xor(tmax, 32));
    const float mn = fmaxf(m, tmax);
    const float alpha = exp2f((m - mn) * L2E);
    m = mn;
    float ps = 0.f;
#pragma unroll
    for (int ni = 0; ni < 4; ++ni) {
      us4 pk;
#pragma unroll
      for (int r = 0; r < 4; ++r) {
        float p = exp2f((sv[ni][r] - mn) * L2E);
        ps += p;
        pk[r] = f2b(p);
      }
      *(us4*)(Ps + (wv * 16 + c) * 72 + ni * 16 + 4 * g) = pk;
    }
    ps += __shfl_xor(ps, 16);
    ps += __shfl_xor(ps, 32);
    l = l * alpha + ps;
    float ar[4];
#pragma unroll
    for (int r = 0; r < 4; ++r) ar[r] = __shfl(alpha, 4 * g + r);
#pragma unroll
    for (int i = 0; i < 8; ++i)
#pragma unroll
      for (int r = 0; r < 4; ++r) acco[i][r] *= ar[r];

    bf16x8 pf0 = *(const bf16x8*)(Ps + (wv * 16 + c) * 72 + 8 * g);
    bf16x8 pf1 = *(const bf16x8*)(Ps + (wv * 16 + c) * 72 + 32 + 8 * g);
#pragma unroll
    for (int nd = 0; nd < 8; ++nd) {
      bf16x8 vf0 = *(const bf16x8*)(Vs + (16 * nd + c) * 72 + 8 * g);
      bf16x8 vf1 = *(const bf16x8*)(Vs + (16 * nd + c) * 72 + 32 + 8 * g);
      acco[nd] = __builtin_amdgcn_mfma_f32_16x16x32_bf16(pf0, vf0, acco[nd], 0, 0, 0);
      acco[nd] = __builtin_amdgcn_mfma_f32_16x16x32_bf16(pf1, vf1, acco[nd], 0, 0, 0);
    }
    __syncthreads();
  }

  const float inv = 1.f / l;
  float ir[4];
#pragma unroll
  for (int r = 0; r < 4; ++r) ir[r] = __shfl(inv, 4 * g + r);
  const int b = bh >> 4, hh = bh & 15;
#pragma unroll
  for (int r = 0; r < 4; ++r) {
    const long tok = (long)((b << 11) | (q0 + wv * 16 + 4 * g + r));
#pragma unroll
    for (int nd = 0; nd < 8; ++nd)
      ab16[tok * 2048 + hh * 128 + nd * 16 + c] = f2b(acco[nd][r] * ir[r]);
  }
}

// ---------------------------------------------------------------------------
// Fused LayerNorm(a), LayerNorm(h), blend -> bf16 (inputs now bf16).
// ---------------------------------------------------------------------------
__global__ __launch_bounds__(256)
void ln_blend(const u16* __restrict__ a, const u16* __restrict__ h,
              u16* __restrict__ ab,
              const float* __restrict__ gate,
              const float* __restrict__ ga, const float* __restrict__ ba,
              const float* __restrict__ gh, const float* __restrict__ bhv)
{
  const int tid = threadIdx.x;
  const long roff = (long)blockIdx.x * 2048 + tid * 8;
  float av[8], hv[8];
  {
    us8 ua = *(const us8*)(a + roff);
    us8 uh = *(const us8*)(h + roff);
#pragma unroll
    for (int i = 0; i < 8; ++i) { av[i] = b2f(ua[i]); hv[i] = b2f(uh[i]); }
  }
  float sa = 0.f, sa2 = 0.f, sh = 0.f, sh2 = 0.f;
#pragma unroll
  for (int i = 0; i < 8; ++i) {
    sa += av[i]; sa2 += av[i] * av[i];
    sh += hv[i]; sh2 += hv[i] * hv[i];
  }
#pragma unroll
  for (int o = 1; o < 64; o <<= 1) {
    sa += __shfl_xor(sa, o); sa2 += __shfl_xor(sa2, o);
    sh += __shfl_xor(sh, o); sh2 += __shfl_xor(sh2, o);
  }
  __shared__ float red[4][4];
  const int wv = tid >> 6;
  if ((tid & 63) == 0) { red[0][wv] = sa; red[1][wv] = sa2; red[2][wv] = sh; red[3][wv] = sh2; }
  __syncthreads();
  sa  = red[0][0] + red[0][1] + red[0][2] + red[0][3];
  sa2 = red[1][0] + red[1][1] + red[1][2] + red[1][3];
  sh  = red[2][0] + red[2][1] + red[2][2] + red[2][3];
  sh2 = red[3][0] + red[3][1] + red[3][2] + red[3][3];
  const float inv = 1.f / 2048.f;
  float ma = sa * inv,  va = sa2 * inv - ma * ma;
  float mh = sh * inv,  vh = sh2 * inv - mh * mh;
  float ra = rsqrtf(va + 1e-5f), rh = rsqrtf(vh + 1e-5f);
  float g = 1.f / (1.f + __expf(-gate[0]));
  g = fminf(fmaxf(g, 0.05f), 0.95f);
  const int j0 = tid * 8;
  us8 o;
#pragma unroll
  for (int i = 0; i < 8; ++i) {
    float aa = (av[i] - ma) * ra * ga[j0 + i] + ba[j0 + i];
    float hn = (hv[i] - mh) * rh * gh[j0 + i] + bhv[j0 + i];
    o[i] = f2b((1.f - g) * aa + g * hn);
  }
  *(us8*)(ab + roff) = o;
}

// ---------------------------------------------------------------------------
extern "C" void kernel_launch(void* const* d_in, const int* in_sizes, int n_in,
                              void* d_out, int out_size, void* d_ws, size_t ws_size,
                              hipStream_t stream)
{
  const float* x    = (const float*)d_in[0];
  const float* cosT = (const float*)d_in[1];
  const float* sinT = (const float*)d_in[2];
  const float* qkvw = (const float*)d_in[3];
  const float* outw = (const float*)d_in[4];
  const float* gate = (const float*)d_in[5];
  const float* ga   = (const float*)d_in[6];
  const float* ba   = (const float*)d_in[7];
  const float* gh   = (const float*)d_in[8];
  const float* bhv  = (const float*)d_in[9];
  float* out = (float*)d_out;

  // workspace map (<=102 MiB):
  //  [0,16M)   qb          -> ab   (ln_blend out, after holo_fwd)
  //  [16,32M)  kb          -> ob   (out_w bf16, after holo_fwd)
  //  [32,48M)  vb
  //  [48,64M)  xb (pre-gemm0) -> ab16 (flash out bf16)
  //  [64,89.2M) wb (pre-gemm0); then P [64,84M), hb16 [84,100M)
  //  [100M,+)  Fm (36.9KB), Cm (40KB)
  char* w = (char*)d_ws;
  u16* qb   = (u16*)w;
  u16* kb   = (u16*)(w + (16u << 20));
  u16* vb   = (u16*)(w + (32u << 20));
  u16* xb   = (u16*)(w + (48u << 20));
  u16* ab16 = (u16*)(w + (48u << 20));
  u16* wb   = (u16*)(w + (64u << 20));
  u16* Pb   = (u16*)(w + (64u << 20));
  u16* hb16 = (u16*)(w + (84u << 20));
  u16* Fm   = (u16*)(w + (100u << 20));
  u16* Cm   = (u16*)(w + (100u << 20) + 40960);
  u16* ob   = kb;
  u16* ab   = qb;

  init_tables<<<152, 256, 0, stream>>>(Fm, Cm);
  convert_bf16<<<4096, 256, 0, stream>>>(x,    xb);
  convert_bf16<<<6144, 256, 0, stream>>>(qkvw, wb);
  gemm_bf16<0><<<1536, 256, 0, stream>>>(xb, wb, nullptr, qb, kb, vb,
                                         cosT, sinT, 4096, 6144, 2048);
  flash_attn<<<dim3(32, 32), 256, 0, stream>>>(qb, kb, vb, ab16);
  holo_fwd<<<512, 512, 0, stream>>>(qb, kb, vb, Fm, Pb);
  gemm_bf16<2><<<512, 256, 0, stream>>>(Pb, Cm, nullptr, hb16, nullptr, nullptr,
                                        nullptr, nullptr, 65536, 128, 160);
  convert_bf16<<<2048, 256, 0, stream>>>(outw, ob);
  ln_blend<<<4096, 256, 0, stream>>>(ab16, hb16, ab, gate, ga, ba, gh, bhv);
  gemm_bf16<1><<<512, 256, 0, stream>>>(ab, ob, out, nullptr, nullptr, nullptr,
                                        nullptr, nullptr, 4096, 2048, 2048);
}

// Round 5
// 366.518 us; speedup vs baseline: 2.1410x; 1.0037x over previous
//
#include <hip/hip_runtime.h>

typedef unsigned short u16;
typedef __attribute__((ext_vector_type(4))) unsigned short us4;
typedef __attribute__((ext_vector_type(8))) unsigned short us8;
typedef __attribute__((ext_vector_type(8))) __bf16 bf16x8;
typedef __attribute__((ext_vector_type(4))) float f32x4;

#define L2E 1.4426950408889634f
#define RSQ128 0.08838834764831845f

__device__ __forceinline__ u16 f2b(float f) {
  unsigned u = __builtin_bit_cast(unsigned, f);
  u += 0x7fffu + ((u >> 16) & 1u);          // round-to-nearest-even
  return (u16)(u >> 16);
}
__device__ __forceinline__ float b2f(u16 s) {
  unsigned u = ((unsigned)s) << 16;
  return __builtin_bit_cast(float, u);
}

__device__ __forceinline__ void gload16(const u16* g, const u16* l) {
  __builtin_amdgcn_global_load_lds(
      (const __attribute__((address_space(1))) unsigned*)g,
      (__attribute__((address_space(3))) unsigned*)l, 16, 0, 0);
}

// ---------------------------------------------------------------------------
// f32 -> bf16 convert, 8 elems/thread.
// ---------------------------------------------------------------------------
__global__ __launch_bounds__(256)
void convert_bf16(const float* __restrict__ src, u16* __restrict__ dst)
{
  const long i = ((long)blockIdx.x * 256 + threadIdx.x) * 8;
  float4 a = *(const float4*)(src + i);
  float4 b = *(const float4*)(src + i + 4);
  us8 o = { f2b(a.x), f2b(a.y), f2b(a.z), f2b(a.w),
            f2b(b.x), f2b(b.y), f2b(b.z), f2b(b.w) };
  *(us8*)(dst + i) = o;
}

// ---------------------------------------------------------------------------
// DFT tables (bf16). See round-3 derivation.
// ---------------------------------------------------------------------------
__global__ __launch_bounds__(256)
void init_tables(u16* __restrict__ Fm, u16* __restrict__ Cm)
{
  const int i = blockIdx.x * 256 + threadIdx.x;
  const float w0 = 6.283185307179586f / 128.f;
  if (i < 144 * 128) {
    const int fc = i >> 7, d = i & 127;
    float v = 0.f;
    if (fc < 130) {
      const int f = fc >> 1;
      const float ang = (float)((f * d) & 127) * w0;
      v = ((fc & 1) == 0 ? cosf(ang) : -sinf(ang)) * RSQ128;
    }
    Fm[i] = f2b(v);
  } else {
    const int j = i - 144 * 128;
    const int t = j / 160, fc = j % 160;
    float v = 0.f;
    if (fc < 130) {
      const int f = fc >> 1;
      if ((fc & 1) == 0) {
        if (f == 0)       v = RSQ128;
        else if (f == 64) v = (t & 1) ? -RSQ128 : RSQ128;
        else              v = 2.f * cosf((float)((f * t) & 127) * w0) * RSQ128;
      } else {
        if (f != 0 && f != 64)
          v = -2.f * sinf((float)((f * t) & 127) * w0) * RSQ128;
      }
    }
    Cm[j] = f2b(v);
  }
}

// ---------------------------------------------------------------------------
// 256x256x64 8-phase bf16 TN GEMM with fused RoPE/scatter epilogue (QKV).
// 512 thr / 8 waves (2M x 4N), per-wave 128x64 output, LDS 128 KiB dbuf.
// T2: XOR involution blk^=(row&7) on 16B blocks (inverse-swz global source
//     + swz ds_read; linear LDS dest for global_load_lds).
// T3/T4: 4 phases per K-tile; stage tile t+1 at phases 0-1; single vmcnt(0)
//     at phase-3 end (2-3 phases after issue); raw s_barrier only.
// T5: setprio(1) around each 16-MFMA cluster.
// ---------------------------------------------------------------------------
__global__ __launch_bounds__(512, 1)
void gemm256_qkv(const u16* __restrict__ A, const u16* __restrict__ Bm,
                 u16* __restrict__ qb, u16* __restrict__ kb, u16* __restrict__ vb,
                 const float* __restrict__ cosT, const float* __restrict__ sinT,
                 int M, int N, int K)
{
  __shared__ u16 As[2][256 * 64];
  __shared__ u16 Bs[2][256 * 64];
  const int tid  = threadIdx.x;
  const int lane = tid & 63;
  const int c    = lane & 15;
  const int g    = lane >> 4;
  const int wid  = tid >> 6;
  const int wm   = (wid >> 2) * 128;
  const int wn   = (wid & 3) * 64;

  const int cpx  = gridDim.x >> 3;
  const int flat = blockIdx.x;
  const int swzb = (flat & 7) * cpx + (flat >> 3);
  const int ntx  = N >> 8;
  const int m0 = (swzb / ntx) * 256;
  const int n0 = (swzb % ntx) * 256;

  f32x4 acc[8][4];
#pragma unroll
  for (int i = 0; i < 8; ++i)
#pragma unroll
    for (int j = 0; j < 4; ++j) acc[i][j] = (f32x4)0.f;

  // staging: thread covers rows (tid>>3) of each 64-row chunk, swizzled col
  const int srow = tid >> 3;                      // 0..63
  const int scb  = (tid & 7) ^ (srow & 7);        // swizzled 16B col-block
  const u16* Ag = A  + (long)(m0 + srow) * K + scb * 8;
  const u16* Bg = Bm + (long)(n0 + srow) * K + scb * 8;

  // ds_read swizzled col-block offsets (elements) per k-slice
  const int cx = c & 7;
  const int abk0 = ((0 + g) ^ cx) * 8;
  const int abk1 = ((4 + g) ^ cx) * 8;

  bf16x8 Am[4], Bk[4];

#define STAGEA(DB, HT, J, K0) \
  gload16(Ag + (long)((HT) * 128 + (J) * 64) * K + (K0), \
          &As[DB][(HT) * 8192 + (J) * 4096 + wid * 512])
#define STAGEB(DB, HT, J, K0) \
  gload16(Bg + (long)((HT) * 128 + (J) * 64) * K + (K0), \
          &Bs[DB][(HT) * 8192 + (J) * 4096 + wid * 512])
#define LOADA(ABK, MOFF) \
  _Pragma("unroll") \
  for (int mt = 0; mt < 4; ++mt) \
    Am[mt] = *(const bf16x8*)(Ac + (wm + ((MOFF) + mt) * 16 + c) * 64 + (ABK));
#define LOADB(ABK) \
  _Pragma("unroll") \
  for (int nt = 0; nt < 4; ++nt) \
    Bk[nt] = *(const bf16x8*)(Bc + (wn + nt * 16 + c) * 64 + (ABK));
#define MFMA16(MOFF) \
  __builtin_amdgcn_s_setprio(1); \
  _Pragma("unroll") \
  for (int mt = 0; mt < 4; ++mt) \
    _Pragma("unroll") \
    for (int nt = 0; nt < 4; ++nt) \
      acc[(MOFF) + mt][nt] = __builtin_amdgcn_mfma_f32_16x16x32_bf16( \
          Am[mt], Bk[nt], acc[(MOFF) + mt][nt], 0, 0, 0); \
  __builtin_amdgcn_s_setprio(0);
#define BAR()   __builtin_amdgcn_s_barrier()
#define LGKM0() do { asm volatile("s_waitcnt lgkmcnt(0)" ::: "memory"); \
                     __builtin_amdgcn_sched_barrier(0); } while (0)
#define VM0()   asm volatile("s_waitcnt vmcnt(0)" ::: "memory")

  // prologue: stage tile 0 into buf 0
  STAGEA(0, 0, 0, 0); STAGEA(0, 0, 1, 0); STAGEA(0, 1, 0, 0); STAGEA(0, 1, 1, 0);
  STAGEB(0, 0, 0, 0); STAGEB(0, 0, 1, 0); STAGEB(0, 1, 0, 0); STAGEB(0, 1, 1, 0);
  VM0();
  BAR();

  const int NT = K >> 6;
  for (int t = 0; t < NT; ++t) {
    const int cb = t & 1;
    const u16* Ac = As[cb];
    const u16* Bc = Bs[cb];
    const int nk0 = (t + 1) << 6;
    const bool more = (t + 1 < NT);
    // ---- phase 0: k-slice 0, m 0..3 ----
    LOADA(abk0, 0); LOADB(abk0);
    if (more) { STAGEA(1 - cb, 0, 0, nk0); STAGEA(1 - cb, 0, 1, nk0);
                STAGEA(1 - cb, 1, 0, nk0); STAGEA(1 - cb, 1, 1, nk0); }
    BAR(); LGKM0();
    MFMA16(0);
    BAR();
    // ---- phase 1: k-slice 0, m 4..7 ----
    LOADA(abk0, 4);
    if (more) { STAGEB(1 - cb, 0, 0, nk0); STAGEB(1 - cb, 0, 1, nk0);
                STAGEB(1 - cb, 1, 0, nk0); STAGEB(1 - cb, 1, 1, nk0); }
    BAR(); LGKM0();
    MFMA16(4);
    BAR();
    // ---- phase 2: k-slice 1, m 0..3 ----
    LOADA(abk1, 0); LOADB(abk1);
    BAR(); LGKM0();
    MFMA16(0);
    BAR();
    // ---- phase 3: k-slice 1, m 4..7 ----
    LOADA(abk1, 4);
    BAR(); LGKM0();
    MFMA16(4);
    if (more) VM0();     // drains stage(t+1), issued 2-3 phases ago
    BAR();
  }

  // epilogue: RoPE + scatter to per-head q/k/v
  const int w = n0 >> 11;
#pragma unroll
  for (int mt = 0; mt < 8; ++mt) {
    const int rowb = m0 + wm + mt * 16 + g * 4;
#pragma unroll
    for (int nt = 0; nt < 4; ++nt) {
      const int nn = n0 + wn + nt * 16 + c;
      const int hh = (nn >> 7) & 15;
      const int d  = nn & 127;
#pragma unroll
      for (int r = 0; r < 4; ++r) {
        float val = acc[mt][nt][r];
        float oth = __shfl_xor(val, 1);
        const int tok = rowb + r;
        const int s   = tok & 2047;
        const long idx = ((long)(((tok >> 11) << 4) | hh) * 2048 + s) * 128 + d;
        if (w == 2) {
          vb[idx] = f2b(val);
        } else {
          float cc = cosT[s * 64 + (d >> 1)];
          float sn = sinT[s * 64 + (d >> 1)];
          float res = (d & 1) ? (oth * sn + val * cc) : (val * cc - oth * sn);
          ((w == 0) ? qb : kb)[idx] = f2b(res);
        }
      }
    }
  }
#undef STAGEA
#undef STAGEB
#undef LOADA
#undef LOADB
#undef MFMA16
#undef BAR
#undef LGKM0
#undef VM0
}

// ---------------------------------------------------------------------------
// m97-structure bf16 TN GEMM (kept for OUT GEMM and holo inverse).
// MODE 1: plain f32 store. MODE 2: holo inverse-DFT scatter (bf16).
// ---------------------------------------------------------------------------
template<int MODE>
__global__ __launch_bounds__(256, 3)
void gemm_bf16(const u16* __restrict__ A, const u16* __restrict__ Bm,
               float* __restrict__ Cout,
               u16* __restrict__ qb,
               int M, int N, int K)
{
  __shared__ u16 As[128 * 32];
  __shared__ u16 Bs[128 * 32];
  const int tid  = threadIdx.x;
  const int lane = tid & 63;
  const int wid  = tid >> 6;
  const int c    = lane & 15;
  const int g    = lane >> 4;

  const int cpx  = gridDim.x >> 3;
  const int flat = blockIdx.x;
  const int swz  = (flat & 7) * cpx + (flat >> 3);
  const int ntx  = N >> 7;
  const int m0 = (swz / ntx) * 128;
  const int n0 = (swz % ntx) * 128;
  const int wm = (wid >> 1) * 64;
  const int wn = (wid & 1) * 64;

  f32x4 acc[4][4];
#pragma unroll
  for (int i = 0; i < 4; ++i)
#pragma unroll
    for (int j = 0; j < 4; ++j) acc[i][j] = (f32x4)0.f;

  const int srow = lane >> 2;
  const int scol = ((lane & 3) ^ ((srow >> 1) & 3)) << 3;
  const u16* Ag0 = A  + (long)(m0 + wid * 32 + srow) * K + scol;
  const u16* Ag1 = Ag0 + (long)16 * K;
  const u16* Bg0 = Bm + (long)(n0 + wid * 32 + srow) * K + scol;
  const u16* Bg1 = Bg0 + (long)16 * K;
  const u16* la0 = &As[(wid * 32) * 32];
  const u16* la1 = &As[(wid * 32 + 16) * 32];
  const u16* lb0 = &Bs[(wid * 32) * 32];
  const u16* lb1 = &Bs[(wid * 32 + 16) * 32];

  int aoff[4], boff[4];
#pragma unroll
  for (int mi = 0; mi < 4; ++mi) {
    int rl = wm + mi * 16 + c;
    aoff[mi] = rl * 32 + ((g ^ ((rl >> 1) & 3)) << 3);
  }
#pragma unroll
  for (int ni = 0; ni < 4; ++ni) {
    int rl = wn + ni * 16 + c;
    boff[ni] = rl * 32 + ((g ^ ((rl >> 1) & 3)) << 3);
  }

  for (int k0 = 0; k0 < K; k0 += 32) {
    gload16(Ag0 + k0, la0);
    gload16(Ag1 + k0, la1);
    gload16(Bg0 + k0, lb0);
    gload16(Bg1 + k0, lb1);
    __syncthreads();

    bf16x8 af[4], bfr[4];
#pragma unroll
    for (int mi = 0; mi < 4; ++mi) af[mi]  = *(const bf16x8*)(As + aoff[mi]);
#pragma unroll
    for (int ni = 0; ni < 4; ++ni) bfr[ni] = *(const bf16x8*)(Bs + boff[ni]);
#pragma unroll
    for (int mi = 0; mi < 4; ++mi)
#pragma unroll
      for (int ni = 0; ni < 4; ++ni)
        acc[mi][ni] = __builtin_amdgcn_mfma_f32_16x16x32_bf16(af[mi], bfr[ni], acc[mi][ni], 0, 0, 0);
    __syncthreads();
  }

  if (MODE == 1) {
#pragma unroll
    for (int mi = 0; mi < 4; ++mi) {
      const int rowb = m0 + wm + mi * 16 + g * 4;
#pragma unroll
      for (int ni = 0; ni < 4; ++ni) {
        const int col = n0 + wn + ni * 16 + c;
#pragma unroll
        for (int r = 0; r < 4; ++r)
          Cout[(long)(rowb + r) * N + col] = acc[mi][ni][r];
      }
    }
  } else {
    // MODE 2: rows are (bh*2048+s); write bf16 holo into token layout via qb
#pragma unroll
    for (int mi = 0; mi < 4; ++mi) {
      const int rowb = m0 + wm + mi * 16 + g * 4;
#pragma unroll
      for (int ni = 0; ni < 4; ++ni) {
        const int t = wn + ni * 16 + c;   // 0..127
#pragma unroll
        for (int r = 0; r < 4; ++r) {
          const int row = rowb + r;
          const int bh = row >> 11, s = row & 2047;
          const long addr = ((long)(((bh >> 4) << 11) | s) << 11) + ((bh & 15) << 7) + t;
          qb[addr] = f2b(acc[mi][ni][r]);
        }
      }
    }
  }
}

// ---------------------------------------------------------------------------
// Holographic forward: Qf/Kf/Vf = rows @ F (fused 3x GEMM, shared B), then
// P = conj(Qf)*Kf*Vf elementwise (re/im adjacent lanes -> shfl_xor(1)).
// ---------------------------------------------------------------------------
__global__ __launch_bounds__(512, 1)
void holo_fwd(const u16* __restrict__ qb, const u16* __restrict__ kb,
              const u16* __restrict__ vb, const u16* __restrict__ Fm,
              u16* __restrict__ P)
{
  __shared__ u16 Fs[144 * 128];
  const int tid = threadIdx.x, lane = tid & 63, wv = tid >> 6;
  const int c = lane & 15, g = lane >> 4;
  const long row0 = (long)blockIdx.x * 128;

  for (int i = tid; i < 144 * 16; i += 512) {
    const int fc = i >> 4, d8 = (i & 15) << 3;
    us8 v = *(const us8*)(Fm + fc * 128 + d8);
    *(us8*)((char*)Fs + ((fc * 256 + d8 * 2) ^ ((fc & 7) << 4))) = v;
  }

  const long ar = row0 + wv * 16 + c;
  bf16x8 aq[4], ak[4], av[4];
#pragma unroll
  for (int ks = 0; ks < 4; ++ks) {
    aq[ks] = *(const bf16x8*)(qb + ar * 128 + 32 * ks + 8 * g);
    ak[ks] = *(const bf16x8*)(kb + ar * 128 + 32 * ks + 8 * g);
    av[ks] = *(const bf16x8*)(vb + ar * 128 + 32 * ks + 8 * g);
  }
  __syncthreads();

  f32x4 accq[9], acck[9], accv[9];
#pragma unroll
  for (int nt = 0; nt < 9; ++nt) {
    accq[nt] = (f32x4)0.f; acck[nt] = (f32x4)0.f; accv[nt] = (f32x4)0.f;
  }
#pragma unroll
  for (int nt = 0; nt < 9; ++nt) {
    const int fc = nt * 16 + c;
    const int sw = (fc & 7) << 4;
#pragma unroll
    for (int ks = 0; ks < 4; ++ks) {
      bf16x8 bf = *(const bf16x8*)((char*)Fs + ((fc * 256 + (32 * ks + 8 * g) * 2) ^ sw));
      accq[nt] = __builtin_amdgcn_mfma_f32_16x16x32_bf16(aq[ks], bf, accq[nt], 0, 0, 0);
      acck[nt] = __builtin_amdgcn_mfma_f32_16x16x32_bf16(ak[ks], bf, acck[nt], 0, 0, 0);
      accv[nt] = __builtin_amdgcn_mfma_f32_16x16x32_bf16(av[ks], bf, accv[nt], 0, 0, 0);
    }
  }

  const bool even = ((c & 1) == 0);
  const long prow = row0 + wv * 16 + 4 * g;
#pragma unroll
  for (int nt = 0; nt < 9; ++nt) {
#pragma unroll
    for (int r = 0; r < 4; ++r) {
      float q = accq[nt][r], k = acck[nt][r], v = accv[nt][r];
      float xq = __shfl_xor(q, 1), xk = __shfl_xor(k, 1), xv = __shfl_xor(v, 1);
      float bc = even ? (k * v - xk * xv) : (xk * v + k * xv);
      float xbc = __shfl_xor(bc, 1);
      float p = even ? (q * bc + xq * xbc) : (xq * bc - q * xbc);
      P[(prow + r) * 160 + nt * 16 + c] = f2b(p);
    }
  }
#pragma unroll
  for (int r = 0; r < 4; ++r) P[(prow + r) * 160 + 144 + c] = 0;
}

// ---------------------------------------------------------------------------
// Causal flash attention (swapped-operand), bf16 output.
// ---------------------------------------------------------------------------
__global__ __launch_bounds__(256, 3)
void flash_attn(const u16* __restrict__ qb, const u16* __restrict__ kb,
                const u16* __restrict__ vb, u16* __restrict__ ab16)
{
  __shared__ u16 Ks[64 * 140];
  __shared__ u16 Vs[128 * 72];
  __shared__ u16 Ps[64 * 72];
  const int tid  = threadIdx.x;
  const int lane = tid & 63;
  const int wv   = tid >> 6;
  const int c    = lane & 15;
  const int g    = lane >> 4;
  const int bh = blockIdx.x;
  const int qt = 31 - blockIdx.y;
  const int q0 = qt * 64;
  const long basek = (long)bh * 2048 * 128;

  bf16x8 qf[4];
  {
    const u16* qptr = qb + basek + (long)(q0 + wv * 16 + c) * 128 + 8 * g;
#pragma unroll
    for (int ks = 0; ks < 4; ++ks) qf[ks] = *(const bf16x8*)(qptr + 32 * ks);
  }
  f32x4 acco[8];
#pragma unroll
  for (int i = 0; i < 8; ++i) acco[i] = (f32x4)0.f;
  float m = -1e30f, l = 0.f;

  const int skv = tid >> 2;
  const int sdu = (tid & 3) * 32;
  const int vkp = tid & 31;
  const int vdb = (tid >> 5) * 8;

  const int nt = qt + 1;
  for (int t = 0; t < nt; ++t) {
    const int kv0 = t * 64;
    {
      const u16* kp = kb + basek + (long)(kv0 + skv) * 128 + sdu;
#pragma unroll
      for (int u = 0; u < 4; ++u)
        *(us8*)(Ks + skv * 140 + sdu + 8 * u) = *(const us8*)(kp + 8 * u);
#pragma unroll
      for (int h = 0; h < 2; ++h) {
        const int d0 = vdb + 64 * h;
        const u16* vp = vb + basek + (long)(kv0 + 2 * vkp) * 128 + d0;
        us8 v0 = *(const us8*)vp;
        us8 v1 = *(const us8*)(vp + 128);
#pragma unroll
        for (int j = 0; j < 8; ++j) {
          unsigned pk = (unsigned)v0[j] | ((unsigned)v1[j] << 16);
          *(unsigned*)(Vs + (d0 + j) * 72 + 2 * vkp) = pk;
        }
      }
    }
    __syncthreads();

    f32x4 accs[4];
#pragma unroll
    for (int i = 0; i < 4; ++i) accs[i] = (f32x4)0.f;
#pragma unroll
    for (int ni = 0; ni < 4; ++ni)
#pragma unroll
      for (int ks = 0; ks < 4; ++ks) {
        bf16x8 kf = *(const bf16x8*)(Ks + (ni * 16 + c) * 140 + 32 * ks + 8 * g);
        accs[ni] = __builtin_amdgcn_mfma_f32_16x16x32_bf16(kf, qf[ks], accs[ni], 0, 0, 0);
      }

    float sv[4][4];
    float tmax = -1e30f;
    const bool lastt = (t == nt - 1);
#pragma unroll
    for (int ni = 0; ni < 4; ++ni)
#pragma unroll
      for (int r = 0; r < 4; ++r) {
        float s = accs[ni][r] * RSQ128;
        if (lastt && (kv0 + ni * 16 + 4 * g + r > q0 + wv * 16 + c)) s = -1e30f;
        sv[ni][r] = s;
        tmax = fmaxf(tmax, s);
      }
    tmax = fmaxf(tmax, __shfl_xor(tmax, 16));
    tmax = fmaxf(tmax, __shfl_xor(tmax, 32));
    const float mn = fmaxf(m, tmax);
    const float alpha = exp2f((m - mn) * L2E);
    m = mn;
    float ps = 0.f;
#pragma unroll
    for (int ni = 0; ni < 4; ++ni) {
      us4 pk;
#pragma unroll
      for (int r = 0; r < 4; ++r) {
        float p = exp2f((sv[ni][r] - mn) * L2E);
        ps += p;
        pk[r] = f2b(p);
      }
      *(us4*)(Ps + (wv * 16 + c) * 72 + ni * 16 + 4 * g) = pk;
    }
    ps += __shfl_xor(ps, 16);
    ps += __shfl_xor(ps, 32);
    l = l * alpha + ps;
    float ar[4];
#pragma unroll
    for (int r = 0; r < 4; ++r) ar[r] = __shfl(alpha, 4 * g + r);
#pragma unroll
    for (int i = 0; i < 8; ++i)
#pragma unroll
      for (int r = 0; r < 4; ++r) acco[i][r] *= ar[r];

    bf16x8 pf0 = *(const bf16x8*)(Ps + (wv * 16 + c) * 72 + 8 * g);
    bf16x8 pf1 = *(const bf16x8*)(Ps + (wv * 16 + c) * 72 + 32 + 8 * g);
#pragma unroll
    for (int nd = 0; nd < 8; ++nd) {
      bf16x8 vf0 = *(const bf16x8*)(Vs + (16 * nd + c) * 72 + 8 * g);
      bf16x8 vf1 = *(const bf16x8*)(Vs + (16 * nd + c) * 72 + 32 + 8 * g);
      acco[nd] = __builtin_amdgcn_mfma_f32_16x16x32_bf16(pf0, vf0, acco[nd], 0, 0, 0);
      acco[nd] = __builtin_amdgcn_mfma_f32_16x16x32_bf16(pf1, vf1, acco[nd], 0, 0, 0);
    }
    __syncthreads();
  }

  const float inv = 1.f / l;
  float ir[4];
#pragma unroll
  for (int r = 0; r < 4; ++r) ir[r] = __shfl(inv, 4 * g + r);
  const int b = bh >> 4, hh = bh & 15;
#pragma unroll
  for (int r = 0; r < 4; ++r) {
    const long tok = (long)((b << 11) | (q0 + wv * 16 + 4 * g + r));
#pragma unroll
    for (int nd = 0; nd < 8; ++nd)
      ab16[tok * 2048 + hh * 128 + nd * 16 + c] = f2b(acco[nd][r] * ir[r]);
  }
}

// ---------------------------------------------------------------------------
// Fused LayerNorm(a), LayerNorm(h), blend -> bf16 (inputs bf16).
// ---------------------------------------------------------------------------
__global__ __launch_bounds__(256)
void ln_blend(const u16* __restrict__ a, const u16* __restrict__ h,
              u16* __restrict__ ab,
              const float* __restrict__ gate,
              const float* __restrict__ ga, const float* __restrict__ ba,
              const float* __restrict__ gh, const float* __restrict__ bhv)
{
  const int tid = threadIdx.x;
  const long roff = (long)blockIdx.x * 2048 + tid * 8;
  float av[8], hv[8];
  {
    us8 ua = *(const us8*)(a + roff);
    us8 uh = *(const us8*)(h + roff);
#pragma unroll
    for (int i = 0; i < 8; ++i) { av[i] = b2f(ua[i]); hv[i] = b2f(uh[i]); }
  }
  float sa = 0.f, sa2 = 0.f, sh = 0.f, sh2 = 0.f;
#pragma unroll
  for (int i = 0; i < 8; ++i) {
    sa += av[i]; sa2 += av[i] * av[i];
    sh += hv[i]; sh2 += hv[i] * hv[i];
  }
#pragma unroll
  for (int o = 1; o < 64; o <<= 1) {
    sa += __shfl_xor(sa, o); sa2 += __shfl_xor(sa2, o);
    sh += __shfl_xor(sh, o); sh2 += __shfl_xor(sh2, o);
  }
  __shared__ float red[4][4];
  const int wv = tid >> 6;
  if ((tid & 63) == 0) { red[0][wv] = sa; red[1][wv] = sa2; red[2][wv] = sh; red[3][wv] = sh2; }
  __syncthreads();
  sa  = red[0][0] + red[0][1] + red[0][2] + red[0][3];
  sa2 = red[1][0] + red[1][1] + red[1][2] + red[1][3];
  sh  = red[2][0] + red[2][1] + red[2][2] + red[2][3];
  sh2 = red[3][0] + red[3][1] + red[3][2] + red[3][3];
  const float inv = 1.f / 2048.f;
  float ma = sa * inv,  va = sa2 * inv - ma * ma;
  float mh = sh * inv,  vh = sh2 * inv - mh * mh;
  float ra = rsqrtf(va + 1e-5f), rh = rsqrtf(vh + 1e-5f);
  float g = 1.f / (1.f + __expf(-gate[0]));
  g = fminf(fmaxf(g, 0.05f), 0.95f);
  const int j0 = tid * 8;
  us8 o;
#pragma unroll
  for (int i = 0; i < 8; ++i) {
    float aa = (av[i] - ma) * ra * ga[j0 + i] + ba[j0 + i];
    float hn = (hv[i] - mh) * rh * gh[j0 + i] + bhv[j0 + i];
    o[i] = f2b((1.f - g) * aa + g * hn);
  }
  *(us8*)(ab + roff) = o;
}

// ---------------------------------------------------------------------------
extern "C" void kernel_launch(void* const* d_in, const int* in_sizes, int n_in,
                              void* d_out, int out_size, void* d_ws, size_t ws_size,
                              hipStream_t stream)
{
  const float* x    = (const float*)d_in[0];
  const float* cosT = (const float*)d_in[1];
  const float* sinT = (const float*)d_in[2];
  const float* qkvw = (const float*)d_in[3];
  const float* outw = (const float*)d_in[4];
  const float* gate = (const float*)d_in[5];
  const float* ga   = (const float*)d_in[6];
  const float* ba   = (const float*)d_in[7];
  const float* gh   = (const float*)d_in[8];
  const float* bhv  = (const float*)d_in[9];
  float* out = (float*)d_out;

  char* w = (char*)d_ws;
  u16* qb   = (u16*)w;
  u16* kb   = (u16*)(w + (16u << 20));
  u16* vb   = (u16*)(w + (32u << 20));
  u16* xb   = (u16*)(w + (48u << 20));
  u16* ab16 = (u16*)(w + (48u << 20));
  u16* wb   = (u16*)(w + (64u << 20));
  u16* Pb   = (u16*)(w + (64u << 20));
  u16* hb16 = (u16*)(w + (84u << 20));
  u16* Fm   = (u16*)(w + (100u << 20));
  u16* Cm   = (u16*)(w + (100u << 20) + 40960);
  u16* ob   = kb;
  u16* ab   = qb;

  init_tables<<<152, 256, 0, stream>>>(Fm, Cm);
  convert_bf16<<<4096, 256, 0, stream>>>(x,    xb);
  convert_bf16<<<6144, 256, 0, stream>>>(qkvw, wb);
  gemm256_qkv<<<384, 512, 0, stream>>>(xb, wb, qb, kb, vb,
                                       cosT, sinT, 4096, 6144, 2048);
  flash_attn<<<dim3(32, 32), 256, 0, stream>>>(qb, kb, vb, ab16);
  holo_fwd<<<512, 512, 0, stream>>>(qb, kb, vb, Fm, Pb);
  gemm_bf16<2><<<512, 256, 0, stream>>>(Pb, Cm, nullptr, hb16,
                                        65536, 128, 160);
  convert_bf16<<<2048, 256, 0, stream>>>(outw, ob);
  ln_blend<<<4096, 256, 0, stream>>>(ab16, hb16, ab, gate, ga, ba, gh, bhv);
  gemm_bf16<1><<<512, 256, 0, stream>>>(ab, ob, out, nullptr,
                                        4096, 2048, 2048);
}